// Round 8
// baseline (567.612 us; speedup 1.0000x reference)
//
#include <hip/hip_runtime.h>
#include <hip/hip_bf16.h>
#include <math.h>

#define NN 2
#define CC 512
#define PP 6272            // T*H*W
#define TCHMAX 1664        // max chunk rows (13 tiles of 128)
#define NCHK 4             // chunks: 13,12,12,12 tiles
#define NJT 49             // PP/128 j-tiles per energy row
#define EM 64.0f           // fixed softmax shift (softmax is shift-invariant)
static const size_t PPC = (size_t)PP * CC;   // per-n projection elems
static const size_t NCP = (size_t)NN * PPC;  // 6,422,528

typedef unsigned short ushortT;
typedef __attribute__((ext_vector_type(8))) short short8;   // 8 bf16 = 4 VGPR
typedef __attribute__((ext_vector_type(4))) float f32x4;

// counted waitcnt (T4): keep newest stages in flight across the barrier
#define WAITV(N) asm volatile("s_waitcnt vmcnt(" #N ")" ::: "memory")
#define BAR() __builtin_amdgcn_s_barrier()

__device__ __forceinline__ ushortT f2bf(float f) {
  __hip_bfloat16 h = __float2bfloat16(f);
  return *reinterpret_cast<ushortT*>(&h);
}
__device__ __forceinline__ float bf2f(ushortT u) {
  return __uint_as_float(((unsigned)u) << 16);
}

// async global->LDS, 16B/lane. LDS dest = wave-uniform base + lane*16.
__device__ __forceinline__ void ld_g2l(const void* g, void* l) {
  __builtin_amdgcn_global_load_lds(
      (const __attribute__((address_space(1))) void*)g,
      (__attribute__((address_space(3))) void*)l, 16, 0, 0);
}

// bijective XCD-chunked remap (m204)
__device__ __forceinline__ int xcd_remap(int orig, int nwg) {
  const int q = nwg >> 3, r = nwg & 7;
  const int x = orig & 7, lo = orig >> 3;
  return (x < r) ? x * (q + 1) + lo : r * (q + 1) + (x - r) * q + lo;
}

// ---------------------------------------------------------------------------
// BK=32 staging. LDS tile [rows][32k], row stride 64B, XOR swizzle
// g ^= (row>>1)&3; store-side lane const (l>>3)&3, read-side (lr>>1)&3.
// k_convs: 3-deep (R5 verbatim). k_energy/k_me: 4-deep, named-pointer
// rotation + conditional tail (2 iterations of load slack).
// ---------------------------------------------------------------------------

// ---------------------------------------------------------------------------
// prep: fused weight-cast (blocks <1024) + transpose-cast x/mask (rest)
// ---------------------------------------------------------------------------
__global__ __launch_bounds__(256) void k_prep(const float* __restrict__ x,
                                              const float* __restrict__ mask,
                                              const float* __restrict__ W0,
                                              const float* __restrict__ W1,
                                              const float* __restrict__ W2,
                                              const float* __restrict__ W3,
                                              ushortT* __restrict__ Wbf,
                                              ushortT* __restrict__ xT,
                                              ushortT* __restrict__ maskT) {
  __shared__ float T[32][33];
  const int tid = threadIdx.x;
  int b = blockIdx.x;
  if (b < 1024) {
    const int by = b >> 8, bx = b & 255;
    const float* src = (by == 0) ? W0 : (by == 1) ? W1 : (by == 2) ? W2 : W3;
    const int i = (bx * 256 + tid) * 4;
    float4 v = *(const float4*)&src[i];
    ushort4 o;
    o.x = f2bf(v.x); o.y = f2bf(v.y); o.z = f2bf(v.z); o.w = f2bf(v.w);
    *(ushort4*)&Wbf[(size_t)by * CC * CC + i] = o;
    return;
  }
  b -= 1024;
  const int bx = b % 196;
  const int by = (b / 196) & 15;
  const int zz = b / (196 * 16);
  const float* in = (zz < 2) ? x : mask;
  ushortT* out = (zz < 2) ? xT : maskT;
  const int p0 = bx * 32, c0 = by * 32;
  const int tx = tid & 31, ty = tid >> 5;
  const size_t nbi = (size_t)(zz & 1) * PPC;
#pragma unroll
  for (int i = 0; i < 4; ++i)
    T[ty + i * 8][tx] = in[nbi + (size_t)(c0 + ty + i * 8) * PP + p0 + tx];
  __syncthreads();
#pragma unroll
  for (int i = 0; i < 4; ++i) {
    int r = ty + i * 8;
    out[nbi + (size_t)(p0 + r) * CC + c0 + tx] = f2bf(T[tx][r]);
  }
}

// ---------------------------------------------------------------------------
// All five 1x1 convs, one dispatch. 3-deep counted-vmcnt pipeline, BK=32.
// (R5 body verbatim — HW-verified.)
// ---------------------------------------------------------------------------
__global__ __launch_bounds__(256, 2) void k_convs(
    const ushortT* __restrict__ xT, const ushortT* __restrict__ maskT,
    const ushortT* __restrict__ Whbf, const ushortT* __restrict__ Wgbf,
    const ushortT* __restrict__ Wmbf, const ushortT* __restrict__ Wzbf,
    const float* __restrict__ bh, const float* __restrict__ bg,
    const float* __restrict__ bm, const float* __restrict__ bz,
    ushortT* __restrict__ phxT, ushortT* __restrict__ pgT,
    ushortT* __restrict__ phmB, ushortT* __restrict__ pmB,
    ushortT* __restrict__ wzb) {
  __shared__ __align__(16) ushortT smem[36864];   // 9 x 8KB (3 mats x 3 bufs)
  const int tid = threadIdx.x;
  const int l = tid & 63, w = tid >> 6;
  const int orig = blockIdx.x;                    // 1176 = 8*147
  const int wgid = (orig & 7) * 147 + (orig >> 3);
  const int zq = wgid / 196;
  const int within = wgid % 196;
  const int ctile = within & 3;
  const int ptile = within >> 2;
  const int wA = (w & 1) * 64, wB = (w >> 1) * 64;
  const int lr = l & 15, lk = l >> 4;
  const int r4 = (l >> 4) * 4;
  const int srow = l >> 2;
  const int sg8 = ((l & 3) ^ ((l >> 3) & 3)) * 8;
  const int rg16 = (lk ^ ((lr >> 1) & 3)) * 16;

  int offL[4], offR[4];
#pragma unroll
  for (int t = 0; t < 4; ++t) {
    offL[t] = (wA + t * 16 + lr) * 64 + rg16;
    offR[t] = (wB + t * 16 + lr) * 64 + rg16;
  }

  auto stage = [&](const ushortT* src, ushortT* dst) {
#pragma unroll
    for (int i = 0; i < 2; ++i)
      ld_g2l(src + (size_t)(w * 32 + i * 16 + srow) * CC + sg8,
             (char*)dst + (w * 2 + i) * 1024);
  };
  auto ldf = [&](const ushortT* base, const int* off, short8* f) {
#pragma unroll
    for (int t = 0; t < 4; ++t)
      f[t] = *(const short8*)((const char*)base + off[t]);
  };

  ushortT* Ca = smem;          ushortT* Na = smem + 4096;  ushortT* Za = smem + 8192;
  ushortT* Cb = smem + 12288;  ushortT* Nb = smem + 16384; ushortT* Zb = smem + 20480;
  ushortT* Cc = smem + 24576;  ushortT* Nc = smem + 28672; ushortT* Zc = smem + 32768;

  if (zq < 2) {                    // ---- h,g pair: out [p][co] ----
    const int zb = zq;
    const int p0 = ptile * 128, c0 = ctile * 128;
    const ushortT* Ax = xT + (size_t)zb * PPC + (size_t)p0 * CC;
    const ushortT* Bw1 = Whbf + (size_t)c0 * CC;
    const ushortT* Bw2 = Wgbf + (size_t)c0 * CC;
    ushortT* o1 = phxT + (size_t)zb * PPC;
    ushortT* o2 = pgT + (size_t)zb * PPC;
    f32x4 a1[4][4] = {}, a2[4][4] = {};
    stage(Ax, Ca); stage(Bw1, Cb); stage(Bw2, Cc);
    stage(Ax + 32, Na); stage(Bw1 + 32, Nb); stage(Bw2 + 32, Nc);
    WAITV(6); BAR();
    for (int t = 0; t < 16; ++t) {
      if (t < 14) {
        const int k = (t + 2) * 32;
        stage(Ax + k, Za); stage(Bw1 + k, Zb); stage(Bw2 + k, Zc);
      }
      short8 fp[4], fw[4];
      ldf(Ca, offL, fp);
      ldf(Cb, offR, fw);
      __builtin_amdgcn_s_setprio(1);
#pragma unroll
      for (int ss = 0; ss < 4; ++ss)
#pragma unroll
        for (int tt = 0; tt < 4; ++tt)
          a1[ss][tt] = __builtin_amdgcn_mfma_f32_16x16x32_bf16(fw[ss], fp[tt], a1[ss][tt], 0, 0, 0);
      __builtin_amdgcn_s_setprio(0);
      ldf(Cc, offR, fw);
      __builtin_amdgcn_s_setprio(1);
#pragma unroll
      for (int ss = 0; ss < 4; ++ss)
#pragma unroll
        for (int tt = 0; tt < 4; ++tt)
          a2[ss][tt] = __builtin_amdgcn_mfma_f32_16x16x32_bf16(fw[ss], fp[tt], a2[ss][tt], 0, 0, 0);
      __builtin_amdgcn_s_setprio(0);
      if (t < 14) { WAITV(6); } else { WAITV(0); }
      BAR();
      ushortT* tp;
      tp = Ca; Ca = Na; Na = Za; Za = tp;
      tp = Cb; Cb = Nb; Nb = Zb; Zb = tp;
      tp = Cc; Cc = Nc; Nc = Zc; Zc = tp;
    }
#pragma unroll
    for (int tt = 0; tt < 4; ++tt) {
      const size_t prow = (size_t)(p0 + wA + tt * 16 + lr) * CC;
#pragma unroll
      for (int ss = 0; ss < 4; ++ss) {
        const int co = c0 + wB + ss * 16 + r4;
        float4 b1v = *(const float4*)&bh[co];
        float4 b2v = *(const float4*)&bg[co];
        ushort4 v1, v2;
        v1.x = f2bf(a1[ss][tt][0] + b1v.x);
        v1.y = f2bf(a1[ss][tt][1] + b1v.y);
        v1.z = f2bf(a1[ss][tt][2] + b1v.z);
        v1.w = f2bf(a1[ss][tt][3] + b1v.w);
        v2.x = f2bf(a2[ss][tt][0] + b2v.x);
        v2.y = f2bf(a2[ss][tt][1] + b2v.y);
        v2.z = f2bf(a2[ss][tt][2] + b2v.z);
        v2.w = f2bf(a2[ss][tt][3] + b2v.w);
        *(ushort4*)&o1[prow + co] = v1;
        *(ushort4*)&o2[prow + co] = v2;
      }
    }
  } else if (zq < 4) {             // ---- mask conv: phm [c][s] ----
    const int zb = zq - 2;
    const int s0 = ptile * 128, c0 = ctile * 128;
    const ushortT* Am = maskT + (size_t)zb * PPC + (size_t)s0 * CC;
    const ushortT* Bw = Whbf + (size_t)c0 * CC;
    ushortT* o = phmB + (size_t)zb * PPC;
    f32x4 a[4][4] = {};
    stage(Am, Ca); stage(Bw, Cb);
    stage(Am + 32, Na); stage(Bw + 32, Nb);
    WAITV(4); BAR();
    for (int t = 0; t < 16; ++t) {
      if (t < 14) {
        const int k = (t + 2) * 32;
        stage(Am + k, Za); stage(Bw + k, Zb);
      }
      short8 fs[4], fc[4];
      ldf(Ca, offL, fs);
      ldf(Cb, offR, fc);
      __builtin_amdgcn_s_setprio(1);
#pragma unroll
      for (int ss = 0; ss < 4; ++ss)
#pragma unroll
        for (int tt = 0; tt < 4; ++tt)
          a[ss][tt] = __builtin_amdgcn_mfma_f32_16x16x32_bf16(fs[ss], fc[tt], a[ss][tt], 0, 0, 0);
      __builtin_amdgcn_s_setprio(0);
      if (t < 14) { WAITV(4); } else { WAITV(0); }
      BAR();
      ushortT* tp;
      tp = Ca; Ca = Na; Na = Za; Za = tp;
      tp = Cb; Cb = Nb; Nb = Zb; Zb = tp;
    }
#pragma unroll
    for (int tt = 0; tt < 4; ++tt) {
      const int c = c0 + wB + tt * 16 + lr;
      const float bi = bh[c];
      const size_t crow = (size_t)c * PP;
#pragma unroll
      for (int ss = 0; ss < 4; ++ss) {
        ushort4 v;
        v.x = f2bf(a[ss][tt][0] + bi);
        v.y = f2bf(a[ss][tt][1] + bi);
        v.z = f2bf(a[ss][tt][2] + bi);
        v.w = f2bf(a[ss][tt][3] + bi);
        *(ushort4*)&o[crow + s0 + wA + ss * 16 + r4] = v;
      }
    }
  } else {                         // ---- m,z pair: out [co][p] ----
    const int zb = zq - 4;
    const int p0 = ptile * 128, c0 = ctile * 128;
    const ushortT* Ax = xT + (size_t)zb * PPC + (size_t)p0 * CC;
    const ushortT* Bw1 = Wmbf + (size_t)c0 * CC;
    const ushortT* Bw2 = Wzbf + (size_t)c0 * CC;
    ushortT* o1 = pmB + (size_t)zb * PPC;
    ushortT* o2 = wzb + (size_t)zb * PPC;
    f32x4 a1[4][4] = {}, a2[4][4] = {};
    stage(Ax, Ca); stage(Bw1, Cb); stage(Bw2, Cc);
    stage(Ax + 32, Na); stage(Bw1 + 32, Nb); stage(Bw2 + 32, Nc);
    WAITV(6); BAR();
    for (int t = 0; t < 16; ++t) {
      if (t < 14) {
        const int k = (t + 2) * 32;
        stage(Ax + k, Za); stage(Bw1 + k, Zb); stage(Bw2 + k, Zc);
      }
      short8 fx[4], fw[4];
      ldf(Ca, offL, fx);
      ldf(Cb, offR, fw);
      __builtin_amdgcn_s_setprio(1);
#pragma unroll
      for (int ss = 0; ss < 4; ++ss)
#pragma unroll
        for (int tt = 0; tt < 4; ++tt)
          a1[ss][tt] = __builtin_amdgcn_mfma_f32_16x16x32_bf16(fx[ss], fw[tt], a1[ss][tt], 0, 0, 0);
      __builtin_amdgcn_s_setprio(0);
      ldf(Cc, offR, fw);
      __builtin_amdgcn_s_setprio(1);
#pragma unroll
      for (int ss = 0; ss < 4; ++ss)
#pragma unroll
        for (int tt = 0; tt < 4; ++tt)
          a2[ss][tt] = __builtin_amdgcn_mfma_f32_16x16x32_bf16(fx[ss], fw[tt], a2[ss][tt], 0, 0, 0);
      __builtin_amdgcn_s_setprio(0);
      if (t < 14) { WAITV(6); } else { WAITV(0); }
      BAR();
      ushortT* tp;
      tp = Ca; Ca = Na; Na = Za; Za = tp;
      tp = Cb; Cb = Nb; Nb = Zb; Zb = tp;
      tp = Cc; Cc = Nc; Nc = Zc; Zc = tp;
    }
#pragma unroll
    for (int tt = 0; tt < 4; ++tt) {
      const int c = c0 + wB + tt * 16 + lr;
      const float b1v = bm[c], b2v = bz[c];
      const size_t crow = (size_t)c * PP;
#pragma unroll
      for (int ss = 0; ss < 4; ++ss) {
        const size_t off = crow + p0 + wA + ss * 16 + r4;
        ushort4 v1, v2;
        v1.x = f2bf(a1[ss][tt][0] + b1v);
        v1.y = f2bf(a1[ss][tt][1] + b1v);
        v1.z = f2bf(a1[ss][tt][2] + b1v);
        v1.w = f2bf(a1[ss][tt][3] + b1v);
        v2.x = f2bf(a2[ss][tt][0] + b2v);
        v2.y = f2bf(a2[ss][tt][1] + b2v);
        v2.z = f2bf(a2[ss][tt][2] + b2v);
        v2.w = f2bf(a2[ss][tt][3] + b2v);
        *(ushort4*)&o1[off] = v1;
        *(ushort4*)&o2[off] = v2;
      }
    }
  }
}

// ---------------------------------------------------------------------------
// Energy GEMM, 4-deep counted-vmcnt pipeline, BK=32 (2 iterations of slack).
// Ledger (4 loads/iter): prologue tiles 0-2 (12 loads), WAITV(8) -> tile0
// done. Iter t<13: stage t+3, WAITV(8) -> t+1 done, tiles t+2,t+3 in flight.
// Tail: t==13 WAITV(4); t>=14 WAITV(0). U = exp(E-EM) direct 8B stores.
// ---------------------------------------------------------------------------
__global__ __launch_bounds__(256, 2) void k_energy(const ushortT* __restrict__ phxT,
                                                   const ushortT* __restrict__ pgT,
                                                   ushortT* __restrict__ Ech,
                                                   float* __restrict__ Estat,
                                                   int tbase) {
  __shared__ __align__(16) ushortT smem[32768];   // A,B x 4 bufs x 8KB
  __shared__ float Ss[128][2];
  const int tid = threadIdx.x;
  const int l = tid & 63, w = tid >> 6;
  const int tiles = gridDim.y;
  const int orig = blockIdx.x + NJT * (blockIdx.y + tiles * blockIdx.z);
  const int wgid = xcd_remap(orig, NJT * tiles * NN);
  const int it = wgid % tiles;
  const int jt = (wgid / tiles) % NJT;
  const int z = wgid / (tiles * NJT);
  const int j0 = jt * 128;
  const int i0 = it * 128;
  const ushortT* Arow = phxT + (size_t)z * PPC + (size_t)(tbase + i0) * CC;
  const ushortT* Brow = pgT + (size_t)z * PPC + (size_t)j0 * CC;
  ushortT* out = Ech + (size_t)z * TCHMAX * PP;
  const int wi = (w & 1) * 64, wj = (w >> 1) * 64;
  const int lr = l & 15, lk = l >> 4;
  const int r4 = (l >> 4) * 4;
  const int srow = l >> 2;
  const int sg8 = ((l & 3) ^ ((l >> 3) & 3)) * 8;
  const int rg16 = (lk ^ ((lr >> 1) & 3)) * 16;

  int offA[4], offB[4];
#pragma unroll
  for (int t = 0; t < 4; ++t) {
    offA[t] = (wi + t * 16 + lr) * 64 + rg16;
    offB[t] = (wj + t * 16 + lr) * 64 + rg16;
  }
  auto stage = [&](const ushortT* src, ushortT* dst) {
#pragma unroll
    for (int i = 0; i < 2; ++i)
      ld_g2l(src + (size_t)(w * 32 + i * 16 + srow) * CC + sg8,
             (char*)dst + (w * 2 + i) * 1024);
  };

  ushortT* Ac = smem;          ushortT* An = smem + 4096;
  ushortT* Az = smem + 8192;   ushortT* Aw = smem + 12288;
  ushortT* Bc = smem + 16384;  ushortT* Bn = smem + 20480;
  ushortT* Bz = smem + 24576;  ushortT* Bw = smem + 28672;

  f32x4 acc[4][4] = {};   // [ss][tt]: reg-dim = s, lane-dim = t

  stage(Arow, Ac); stage(Brow, Bc);
  stage(Arow + 32, An); stage(Brow + 32, Bn);
  stage(Arow + 64, Az); stage(Brow + 64, Bz);
  WAITV(8); BAR();
  for (int t = 0; t < 16; ++t) {
    if (t < 13) {
      const int k = (t + 3) * 32;
      stage(Arow + k, Aw); stage(Brow + k, Bw);
    }
    short8 af[4], bfv[4];
#pragma unroll
    for (int tt = 0; tt < 4; ++tt)
      af[tt] = *(const short8*)((const char*)Ac + offA[tt]);
#pragma unroll
    for (int ss = 0; ss < 4; ++ss)
      bfv[ss] = *(const short8*)((const char*)Bc + offB[ss]);
    __builtin_amdgcn_s_setprio(1);
#pragma unroll
    for (int ss = 0; ss < 4; ++ss)
#pragma unroll
      for (int tt = 0; tt < 4; ++tt)
        acc[ss][tt] = __builtin_amdgcn_mfma_f32_16x16x32_bf16(bfv[ss], af[tt], acc[ss][tt], 0, 0, 0);
    __builtin_amdgcn_s_setprio(0);
    if (t < 13) { WAITV(8); } else if (t == 13) { WAITV(4); } else { WAITV(0); }
    BAR();
    ushortT* tp;
    tp = Ac; Ac = An; An = Az; Az = Aw; Aw = tp;
    tp = Bc; Bc = Bn; Bn = Bz; Bz = Bw; Bw = tp;
  }
  // epilogue: exp + direct 8B stores + row-sum (2 shuffles per t-row)
#pragma unroll
  for (int tt = 0; tt < 4; ++tt) {
    const int trow = i0 + wi + tt * 16 + lr;
    ushortT* orow = out + (size_t)trow * PP + j0;
    float sx = 0.f;
#pragma unroll
    for (int ss = 0; ss < 4; ++ss) {
      float u0 = __expf(acc[ss][tt][0] - EM);
      float u1 = __expf(acc[ss][tt][1] - EM);
      float u2 = __expf(acc[ss][tt][2] - EM);
      float u3 = __expf(acc[ss][tt][3] - EM);
      sx += (u0 + u1) + (u2 + u3);
      ushort4 v;
      v.x = f2bf(u0); v.y = f2bf(u1); v.z = f2bf(u2); v.w = f2bf(u3);
      *(ushort4*)&orow[wj + ss * 16 + r4] = v;
    }
    sx += __shfl_xor(sx, 16);
    sx += __shfl_xor(sx, 32);
    if (l < 16) Ss[wi + tt * 16 + l][w >> 1] = sx;
  }
  __syncthreads();
  if (tid < 128) {
    Estat[((size_t)z * TCHMAX + i0 + tid) * NJT + jt] = Ss[tid][0] + Ss[tid][1];
  }
}

// ---------------------------------------------------------------------------
// combine per-row Z partials -> 1/Z
// ---------------------------------------------------------------------------
__global__ __launch_bounds__(256) void k_zcomb(const float* __restrict__ Estat,
                                               float* __restrict__ rowZ, int rows) {
  const int r = blockIdx.x * 256 + threadIdx.x;
  if (r >= NN * rows) return;
  const int z = r / rows, tl = r % rows;
  const float* p = Estat + ((size_t)z * TCHMAX + tl) * NJT;
  float s = 0.f;
#pragma unroll
  for (int j = 0; j < NJT; ++j) s += p[j];
  rowZ[z * TCHMAX + tl] = 1.0f / s;
}

// ---------------------------------------------------------------------------
// me partial, 4-deep counted-vmcnt pipeline, BK=32 (2 iterations of slack).
// Ledger (3 loads/iter): prologue tiles 0-2 (9 loads), WAITV(6) -> tile0
// done. Iter t+3<NT: stage t+3, WAITV(6). Tail: t+3==NT WAITV(3); else 0.
// grid (rows/64, 4, NN*KSPT).
// ---------------------------------------------------------------------------
template <int KSPT>
__global__ __launch_bounds__(256, 3) void k_me(const ushortT* __restrict__ phmB,
                                               const ushortT* __restrict__ Ech,
                                               ushortT* __restrict__ mePart) {
  __shared__ __align__(16) ushortT smem[24576];   // A 4x8KB + B 4x4KB
  const int tid = threadIdx.x;
  const int l = tid & 63, w = tid >> 6;
  const int gx = gridDim.x;
  const int orig = blockIdx.x + gx * (blockIdx.y + 4 * blockIdx.z);
  const int nwg = gx * 4 * (NN * KSPT);
  const int wgid = (orig & 7) * (nwg >> 3) + (orig >> 3);  // nwg % 8 == 0
  const int cb = wgid & 3;
  const int tl = (wgid >> 2) % gx;
  const int bz = (wgid >> 2) / gx;
  const int tl0 = tl * 64;
  const int c0 = cb * 128;
  const int z = bz / KSPT, ks = bz % KSPT;
  const ushortT* Arow = phmB + (size_t)z * PPC + (size_t)c0 * PP;
  const ushortT* Brow = Ech + (size_t)z * TCHMAX * PP + (size_t)tl0 * PP;
  const int wc = (w & 1) * 64, wt = (w >> 1) * 32;
  const int lr = l & 15, lk = l >> 4;
  const int r4 = (l >> 4) * 4;
  const int srow = l >> 2;
  const int sg8 = ((l & 3) ^ ((l >> 3) & 3)) * 8;
  const int rg16 = (lk ^ ((lr >> 1) & 3)) * 16;

  int offA[4], offB[2];
#pragma unroll
  for (int t = 0; t < 4; ++t) offA[t] = (wc + t * 16 + lr) * 64 + rg16;
#pragma unroll
  for (int t = 0; t < 2; ++t) offB[t] = (wt + t * 16 + lr) * 64 + rg16;

  auto stA = [&](const ushortT* src, ushortT* dst) {   // 128 rows
#pragma unroll
    for (int i = 0; i < 2; ++i)
      ld_g2l(src + (size_t)(w * 32 + i * 16 + srow) * PP + sg8,
             (char*)dst + (w * 2 + i) * 1024);
  };
  auto stB = [&](const ushortT* src, ushortT* dst) {   // 64 rows
    ld_g2l(src + (size_t)(w * 16 + srow) * PP + sg8, (char*)dst + w * 1024);
  };

  ushortT* Ac = smem;          ushortT* An = smem + 4096;
  ushortT* Az = smem + 8192;   ushortT* Aw = smem + 12288;
  ushortT* Bc = smem + 16384;  ushortT* Bn = smem + 18432;
  ushortT* Bz = smem + 20480;  ushortT* Bw = smem + 22528;

  f32x4 acc[2][4] = {};   // [tt][ct]: reg-dim = t, lane-dim = c

  const int sBeg = ((ks * 98) / KSPT) * 64;
  const int sEnd = (((ks + 1) * 98) / KSPT) * 64;
  const int NT = (sEnd - sBeg) >> 5;

  stA(Arow + sBeg, Ac); stB(Brow + sBeg, Bc);
  stA(Arow + sBeg + 32, An); stB(Brow + sBeg + 32, Bn);
  stA(Arow + sBeg + 64, Az); stB(Brow + sBeg + 64, Bz);
  WAITV(6); BAR();
  for (int t = 0; t < NT; ++t) {
    if (t + 3 < NT) {
      const int k = sBeg + (t + 3) * 32;
      stA(Arow + k, Aw); stB(Brow + k, Bw);
    }
    short8 af[4], bfv[2];
#pragma unroll
    for (int ct = 0; ct < 4; ++ct)
      af[ct] = *(const short8*)((const char*)Ac + offA[ct]);
#pragma unroll
    for (int tt = 0; tt < 2; ++tt)
      bfv[tt] = *(const short8*)((const char*)Bc + offB[tt]);
    __builtin_amdgcn_s_setprio(1);
#pragma unroll
    for (int tt = 0; tt < 2; ++tt)
#pragma unroll
      for (int ct = 0; ct < 4; ++ct)
        acc[tt][ct] = __builtin_amdgcn_mfma_f32_16x16x32_bf16(bfv[tt], af[ct], acc[tt][ct], 0, 0, 0);
    __builtin_amdgcn_s_setprio(0);
    if (t + 3 < NT) { WAITV(6); } else if (t + 3 == NT) { WAITV(3); } else { WAITV(0); }
    BAR();
    ushortT* tp;
    tp = Ac; Ac = An; An = Az; Az = Aw; Aw = tp;
    tp = Bc; Bc = Bn; Bn = Bz; Bz = Bw; Bw = tp;
  }
  ushortT* out = mePart + ((size_t)(ks * NN + z) * CC) * TCHMAX;
#pragma unroll
  for (int ct = 0; ct < 4; ++ct) {
    const size_t crow = (size_t)(c0 + wc + ct * 16 + lr) * TCHMAX + tl0;
#pragma unroll
    for (int tt = 0; tt < 2; ++tt) {
      ushort4 v;
      v.x = f2bf(acc[tt][ct][0]);
      v.y = f2bf(acc[tt][ct][1]);
      v.z = f2bf(acc[tt][ct][2]);
      v.w = f2bf(acc[tt][ct][3]);
      *(ushort4*)&out[crow + wt + tt * 16 + r4] = v;
    }
  }
}

// ---------------------------------------------------------------------------
// meb[z][c][tbase+tl] (bf16) = (sum over KSPT partials) * rowZinv[tl]
// ---------------------------------------------------------------------------
template <int KSPT>
__global__ __launch_bounds__(256) void k_meadd(const ushortT* __restrict__ mePart,
                                               const float* __restrict__ rowZ,
                                               ushortT* __restrict__ meb,
                                               int tbase, int rows) {
  const int idx = (blockIdx.x * 256 + threadIdx.x) * 4;   // over NN*CC*rows
  const int tl = idx % rows;
  const int c = (idx / rows) % CC;
  const int z = idx / (rows * CC);
  float s0 = 0.f, s1 = 0.f, s2 = 0.f, s3 = 0.f;
#pragma unroll
  for (int ks = 0; ks < KSPT; ++ks) {
    const size_t o = ((size_t)(ks * NN + z) * CC + c) * TCHMAX + tl;
    ushort4 a = *(const ushort4*)&mePart[o];
    s0 += bf2f(a.x); s1 += bf2f(a.y); s2 += bf2f(a.z); s3 += bf2f(a.w);
  }
  const float4 rz = *(const float4*)&rowZ[z * TCHMAX + tl];
  ushort4 v;
  v.x = f2bf(s0 * rz.x); v.y = f2bf(s1 * rz.y);
  v.z = f2bf(s2 * rz.z); v.w = f2bf(s3 * rz.w);
  *(ushort4*)&meb[((size_t)z * CC + c) * PP + tbase + tl] = v;
}

// ---------------------------------------------------------------------------
// stats: fused me-softmax stats (blocks < NN*CC) + BatchNorm stats (rest)
// ---------------------------------------------------------------------------
__global__ __launch_bounds__(256) void k_stats(const ushortT* __restrict__ me,
                                               const ushortT* __restrict__ wz,
                                               float* __restrict__ m2,
                                               float* __restrict__ Z2,
                                               float* __restrict__ mu,
                                               float* __restrict__ rinv) {
  __shared__ float red[256];
  __shared__ float rq[256];
  const int tid = threadIdx.x;
  const int NCH = PP / 8;
  if ((int)blockIdx.x < NN * CC) {
    const ushortT* row = me + (size_t)blockIdx.x * PP;
    float m = -INFINITY;
    for (int i = tid; i < NCH; i += 256) {
      short8 v = *(const short8*)&row[i * 8];
#pragma unroll
      for (int j = 0; j < 8; ++j) m = fmaxf(m, bf2f((ushortT)v[j]));
    }
    red[tid] = m;
    __syncthreads();
    for (int s = 128; s > 0; s >>= 1) {
      if (tid < s) red[tid] = fmaxf(red[tid], red[tid + s]);
      __syncthreads();
    }
    m = red[0];
    __syncthreads();
    float zz = 0.f;
    for (int i = tid; i < NCH; i += 256) {
      short8 v = *(const short8*)&row[i * 8];
#pragma unroll
      for (int j = 0; j < 8; ++j) zz += __expf(bf2f((ushortT)v[j]) - m);
    }
    red[tid] = zz;
    __syncthreads();
    for (int s = 128; s > 0; s >>= 1) {
      if (tid < s) red[tid] += red[tid + s];
      __syncthreads();
    }
    if (tid == 0) { m2[blockIdx.x] = m; Z2[blockIdx.x] = red[0]; }
  } else {
    const int c = blockIdx.x - NN * CC;
    float s = 0.f, q = 0.f;
    for (int n = 0; n < NN; ++n) {
      const ushortT* rowp = wz + (size_t)n * CC * PP + (size_t)c * PP;
      for (int i = tid; i < NCH; i += 256) {
        short8 v = *(const short8*)&rowp[i * 8];
#pragma unroll
        for (int j = 0; j < 8; ++j) {
          float f = bf2f((ushortT)v[j]);
          s += f;
          q += f * f;
        }
      }
    }
    red[tid] = s; rq[tid] = q;
    __syncthreads();
    for (int st = 128; st > 0; st >>= 1) {
      if (tid < st) { red[tid] += red[tid + st]; rq[tid] += rq[tid + st]; }
      __syncthreads();
    }
    if (tid == 0) {
      const float inv_n = 1.0f / (float)(NN * PP);
      float mean = red[0] * inv_n;
      float var = rq[0] * inv_n - mean * mean;
      mu[c] = mean;
      rinv[c] = rsqrtf(var + 1e-5f);
    }
  }
}

__global__ __launch_bounds__(256) void k_final(const ushortT* __restrict__ pmB,
                                               const ushortT* __restrict__ me,
                                               const ushortT* __restrict__ wz,
                                               const float* __restrict__ m2,
                                               const float* __restrict__ Z2,
                                               const float* __restrict__ mu,
                                               const float* __restrict__ rinv,
                                               const float* __restrict__ bnw,
                                               const float* __restrict__ bnb,
                                               const float* __restrict__ gamma,
                                               float* __restrict__ out) {
  const int e4 = blockIdx.x * 256 + threadIdx.x;
  const size_t e = (size_t)e4 * 4;
  const int nc = (int)(e / PP);
  const int c = nc & (CC - 1);
  const float m = m2[nc];
  const float rz = 1.0f / Z2[nc];
  const float mub = mu[c];
  const float ri = rinv[c] * bnw[c];
  const float bb = bnb[c];
  const float g = gamma[0];
  ushort4 pv = *(const ushort4*)&pmB[e];
  ushort4 mev = *(const ushort4*)&me[e];
  ushort4 wzv = *(const ushort4*)&wz[e];
  float4 o;
  o.x = g * bf2f(pv.x) * (__expf(bf2f(mev.x) - m) * rz) + (bf2f(wzv.x) - mub) * ri + bb;
  o.y = g * bf2f(pv.y) * (__expf(bf2f(mev.y) - m) * rz) + (bf2f(wzv.y) - mub) * ri + bb;
  o.z = g * bf2f(pv.z) * (__expf(bf2f(mev.z) - m) * rz) + (bf2f(wzv.z) - mub) * ri + bb;
  o.w = g * bf2f(pv.w) * (__expf(bf2f(mev.w) - m) * rz) + (bf2f(wzv.w) - mub) * ri + bb;
  *(float4*)&out[e] = o;
}

// ---------------------------------------------------------------------------
extern "C" void kernel_launch(void* const* d_in, const int* in_sizes, int n_in,
                              void* d_out, int out_size, void* d_ws, size_t ws_size,
                              hipStream_t stream) {
  (void)in_sizes; (void)n_in; (void)out_size;
  const float* x    = (const float*)d_in[0];
  const float* mask = (const float*)d_in[1];
  const float* Wh   = (const float*)d_in[2];
  const float* bh   = (const float*)d_in[3];
  const float* Wg   = (const float*)d_in[4];
  const float* bg   = (const float*)d_in[5];
  const float* Wm   = (const float*)d_in[6];
  const float* bm   = (const float*)d_in[7];
  const float* Wz   = (const float*)d_in[8];
  const float* bz   = (const float*)d_in[9];
  const float* bnw  = (const float*)d_in[10];
  const float* bnb  = (const float*)d_in[11];
  const float* gam  = (const float*)d_in[12];

  // ---- workspace layout ----
  ushortT* wzb  = (ushortT*)d_ws;                // bf16 [n][c][p]
  ushortT* meb  = wzb + NCP;                     // bf16 [n][c][p]
  ushortT* pmB  = meb + NCP;                     // bf16 [n][c][p]
  ushortT* phxT = pmB + NCP;                     // bf16 [n][t][c]
  ushortT* pgT  = phxT + NCP;                    // bf16 [n][s][c]
  ushortT* phmB = pgT + NCP;                     // bf16 [n][c][s]
  ushortT* Wbf  = phmB + NCP;                    // 4 x 512x512 bf16
  ushortT* Whbf = Wbf;
  ushortT* Wgbf = Wbf + 1 * CC * CC;
  ushortT* Wmbf = Wbf + 2 * CC * CC;
  ushortT* Wzbf = Wbf + 3 * CC * CC;
  float* m2    = (float*)(Wbf + 4 * CC * CC);
  float* Z2    = m2 + NN * CC;
  float* mu    = Z2 + NN * CC;
  float* rin   = mu + CC;
  float* Estat = rin + CC;                       // NN*TCHMAX*NJT  ~0.65 MB
  float* rowZ  = Estat + (size_t)NN * TCHMAX * NJT;  // NN*TCHMAX (1/Z)
  float* region = rowZ + (size_t)NN * TCHMAX + 16;
  ushortT* xT    = (ushortT*)region;             // overlay (conv phase) 25.7 MB
  ushortT* maskT = xT + NCP;
  ushortT* Ech    = (ushortT*)region;            // bf16 U [n][TCHMAX][PP] 41.7 MB
  ushortT* mePart = Ech + (size_t)NN * TCHMAX * PP; // bf16 [KSPT][n][c][TCHMAX]

  const size_t regionOffB = (size_t)((char*)region - (char*)d_ws);
  const size_t need8 = regionOffB +
      ((size_t)NN * TCHMAX * PP + 8ull * NN * CC * TCHMAX) * 2;
  const bool k8 = ws_size >= need8;

  // ---- prep: weight casts + transpose casts, one dispatch ----
  k_prep<<<1024 + 196 * 16 * 4, 256, 0, stream>>>(x, mask, Wh, Wg, Wm, Wz,
                                                  Wbf, xT, maskT);

  // ---- all five 1x1 convs in one dispatch ----
  k_convs<<<1176, 256, 0, stream>>>(xT, maskT, Whbf, Wgbf, Wmbf, Wzbf,
                                    bh, bg, bm, bz, phxT, pgT, phmB, pmB, wzb);

  // ---- attention: 4 chunks, energy(U+Z) -> zcomb -> me -> add(norm) ----
  static const int chunkTiles[NCHK] = {13, 12, 12, 12};
  int tbase = 0;
  for (int ch = 0; ch < NCHK; ++ch) {
    const int tiles = chunkTiles[ch];
    const int rows = tiles * 128;
    dim3 gE(NJT, tiles, NN);
    k_energy<<<gE, 256, 0, stream>>>(phxT, pgT, Ech, Estat, tbase);
    k_zcomb<<<(NN * rows + 255) / 256, 256, 0, stream>>>(Estat, rowZ, rows);
    if (k8) {
      dim3 gM(rows / 64, CC / 128, NN * 8);
      k_me<8><<<gM, 256, 0, stream>>>(phmB, Ech, mePart);
      k_meadd<8><<<NN * CC * rows / 1024, 256, 0, stream>>>(mePart, rowZ, meb,
                                                            tbase, rows);
    } else {
      dim3 gM(rows / 64, CC / 128, NN * 4);
      k_me<4><<<gM, 256, 0, stream>>>(phmB, Ech, mePart);
      k_meadd<4><<<NN * CC * rows / 1024, 256, 0, stream>>>(mePart, rowZ, meb,
                                                            tbase, rows);
    }
    tbase += rows;
  }

  // ---- fused tails ----
  k_stats<<<NN * CC + CC, 256, 0, stream>>>(meb, wzb, m2, Z2, mu, rin);
  const int total4 = (int)(NCP / 4);
  k_final<<<total4 / 256, 256, 0, stream>>>(pmB, meb, wzb, m2, Z2, mu, rin,
                                            bnw, bnb, gam, (float*)d_out);
}

// Round 9
// 515.147 us; speedup vs baseline: 1.1018x; 1.1018x over previous
//
#include <hip/hip_runtime.h>
#include <hip/hip_bf16.h>
#include <math.h>

#define NN 2
#define CC 512
#define PP 6272            // T*H*W
#define TCHMAX 1664        // max chunk rows (13 tiles of 128)
#define NCHK 4             // chunks: 13,12,12,12 tiles
#define NJT 49             // PP/128 j-tiles per energy row
#define EM 64.0f           // fixed softmax shift (softmax is shift-invariant)
static const size_t PPC = (size_t)PP * CC;   // per-n projection elems
static const size_t NCP = (size_t)NN * PPC;  // 6,422,528

typedef unsigned short ushortT;
typedef __attribute__((ext_vector_type(8))) short short8;   // 8 bf16 = 4 VGPR
typedef __attribute__((ext_vector_type(4))) float f32x4;

// counted waitcnt (T4): keep newest stage in flight across the barrier
#define WAITV(N) asm volatile("s_waitcnt vmcnt(" #N ")" ::: "memory")
#define BAR() __builtin_amdgcn_s_barrier()

__device__ __forceinline__ ushortT f2bf(float f) {
  __hip_bfloat16 h = __float2bfloat16(f);
  return *reinterpret_cast<ushortT*>(&h);
}
__device__ __forceinline__ float bf2f(ushortT u) {
  return __uint_as_float(((unsigned)u) << 16);
}

// async global->LDS, 16B/lane. LDS dest = wave-uniform base + lane*16.
__device__ __forceinline__ void ld_g2l(const void* g, void* l) {
  __builtin_amdgcn_global_load_lds(
      (const __attribute__((address_space(1))) void*)g,
      (__attribute__((address_space(3))) void*)l, 16, 0, 0);
}

// bijective XCD-chunked remap (m204)
__device__ __forceinline__ int xcd_remap(int orig, int nwg) {
  const int q = nwg >> 3, r = nwg & 7;
  const int x = orig & 7, lo = orig >> 3;
  return (x < r) ? x * (q + 1) + lo : r * (q + 1) + (x - r) * q + lo;
}

// ---------------------------------------------------------------------------
// BK=32 staging. LDS tile [rows][32k], row stride 64B, XOR swizzle
// g ^= (row>>1)&3; store-side lane const (l>>3)&3, read-side (lr>>1)&3.
// All GEMMs: 3-deep counted pipeline (R5/R7 structure, HW-verified; 4-deep
// at lower occupancy measured WORSE in R8 — depth lever exhausted).
// This round: task-overlap dispatches (E(ch+1)||meadd(ch), M(ch)||zcomb(ch)).
// ---------------------------------------------------------------------------

// ---------------------------------------------------------------------------
// prep: fused weight-cast (blocks <1024) + transpose-cast x/mask (rest)
// ---------------------------------------------------------------------------
__global__ __launch_bounds__(256) void k_prep(const float* __restrict__ x,
                                              const float* __restrict__ mask,
                                              const float* __restrict__ W0,
                                              const float* __restrict__ W1,
                                              const float* __restrict__ W2,
                                              const float* __restrict__ W3,
                                              ushortT* __restrict__ Wbf,
                                              ushortT* __restrict__ xT,
                                              ushortT* __restrict__ maskT) {
  __shared__ float T[32][33];
  const int tid = threadIdx.x;
  int b = blockIdx.x;
  if (b < 1024) {
    const int by = b >> 8, bx = b & 255;
    const float* src = (by == 0) ? W0 : (by == 1) ? W1 : (by == 2) ? W2 : W3;
    const int i = (bx * 256 + tid) * 4;
    float4 v = *(const float4*)&src[i];
    ushort4 o;
    o.x = f2bf(v.x); o.y = f2bf(v.y); o.z = f2bf(v.z); o.w = f2bf(v.w);
    *(ushort4*)&Wbf[(size_t)by * CC * CC + i] = o;
    return;
  }
  b -= 1024;
  const int bx = b % 196;
  const int by = (b / 196) & 15;
  const int zz = b / (196 * 16);
  const float* in = (zz < 2) ? x : mask;
  ushortT* out = (zz < 2) ? xT : maskT;
  const int p0 = bx * 32, c0 = by * 32;
  const int tx = tid & 31, ty = tid >> 5;
  const size_t nbi = (size_t)(zz & 1) * PPC;
#pragma unroll
  for (int i = 0; i < 4; ++i)
    T[ty + i * 8][tx] = in[nbi + (size_t)(c0 + ty + i * 8) * PP + p0 + tx];
  __syncthreads();
#pragma unroll
  for (int i = 0; i < 4; ++i) {
    int r = ty + i * 8;
    out[nbi + (size_t)(p0 + r) * CC + c0 + tx] = f2bf(T[tx][r]);
  }
}

// ---------------------------------------------------------------------------
// All five 1x1 convs, one dispatch. 3-deep counted-vmcnt pipeline, BK=32.
// (R5 body verbatim — HW-verified.)
// ---------------------------------------------------------------------------
__global__ __launch_bounds__(256, 2) void k_convs(
    const ushortT* __restrict__ xT, const ushortT* __restrict__ maskT,
    const ushortT* __restrict__ Whbf, const ushortT* __restrict__ Wgbf,
    const ushortT* __restrict__ Wmbf, const ushortT* __restrict__ Wzbf,
    const float* __restrict__ bh, const float* __restrict__ bg,
    const float* __restrict__ bm, const float* __restrict__ bz,
    ushortT* __restrict__ phxT, ushortT* __restrict__ pgT,
    ushortT* __restrict__ phmB, ushortT* __restrict__ pmB,
    ushortT* __restrict__ wzb) {
  __shared__ __align__(16) ushortT smem[36864];   // 9 x 8KB (3 mats x 3 bufs)
  const int tid = threadIdx.x;
  const int l = tid & 63, w = tid >> 6;
  const int orig = blockIdx.x;                    // 1176 = 8*147
  const int wgid = (orig & 7) * 147 + (orig >> 3);
  const int zq = wgid / 196;
  const int within = wgid % 196;
  const int ctile = within & 3;
  const int ptile = within >> 2;
  const int wA = (w & 1) * 64, wB = (w >> 1) * 64;
  const int lr = l & 15, lk = l >> 4;
  const int r4 = (l >> 4) * 4;
  const int srow = l >> 2;
  const int sg8 = ((l & 3) ^ ((l >> 3) & 3)) * 8;
  const int rg16 = (lk ^ ((lr >> 1) & 3)) * 16;

  int offL[4], offR[4];
#pragma unroll
  for (int t = 0; t < 4; ++t) {
    offL[t] = (wA + t * 16 + lr) * 64 + rg16;
    offR[t] = (wB + t * 16 + lr) * 64 + rg16;
  }

  auto stage = [&](const ushortT* src, ushortT* dst) {
#pragma unroll
    for (int i = 0; i < 2; ++i)
      ld_g2l(src + (size_t)(w * 32 + i * 16 + srow) * CC + sg8,
             (char*)dst + (w * 2 + i) * 1024);
  };
  auto ldf = [&](const ushortT* base, const int* off, short8* f) {
#pragma unroll
    for (int t = 0; t < 4; ++t)
      f[t] = *(const short8*)((const char*)base + off[t]);
  };

  ushortT* Ca = smem;          ushortT* Na = smem + 4096;  ushortT* Za = smem + 8192;
  ushortT* Cb = smem + 12288;  ushortT* Nb = smem + 16384; ushortT* Zb = smem + 20480;
  ushortT* Cc = smem + 24576;  ushortT* Nc = smem + 28672; ushortT* Zc = smem + 32768;

  if (zq < 2) {                    // ---- h,g pair: out [p][co] ----
    const int zb = zq;
    const int p0 = ptile * 128, c0 = ctile * 128;
    const ushortT* Ax = xT + (size_t)zb * PPC + (size_t)p0 * CC;
    const ushortT* Bw1 = Whbf + (size_t)c0 * CC;
    const ushortT* Bw2 = Wgbf + (size_t)c0 * CC;
    ushortT* o1 = phxT + (size_t)zb * PPC;
    ushortT* o2 = pgT + (size_t)zb * PPC;
    f32x4 a1[4][4] = {}, a2[4][4] = {};
    stage(Ax, Ca); stage(Bw1, Cb); stage(Bw2, Cc);
    stage(Ax + 32, Na); stage(Bw1 + 32, Nb); stage(Bw2 + 32, Nc);
    WAITV(6); BAR();
    for (int t = 0; t < 16; ++t) {
      if (t < 14) {
        const int k = (t + 2) * 32;
        stage(Ax + k, Za); stage(Bw1 + k, Zb); stage(Bw2 + k, Zc);
      }
      short8 fp[4], fw[4];
      ldf(Ca, offL, fp);
      ldf(Cb, offR, fw);
      __builtin_amdgcn_s_setprio(1);
#pragma unroll
      for (int ss = 0; ss < 4; ++ss)
#pragma unroll
        for (int tt = 0; tt < 4; ++tt)
          a1[ss][tt] = __builtin_amdgcn_mfma_f32_16x16x32_bf16(fw[ss], fp[tt], a1[ss][tt], 0, 0, 0);
      __builtin_amdgcn_s_setprio(0);
      ldf(Cc, offR, fw);
      __builtin_amdgcn_s_setprio(1);
#pragma unroll
      for (int ss = 0; ss < 4; ++ss)
#pragma unroll
        for (int tt = 0; tt < 4; ++tt)
          a2[ss][tt] = __builtin_amdgcn_mfma_f32_16x16x32_bf16(fw[ss], fp[tt], a2[ss][tt], 0, 0, 0);
      __builtin_amdgcn_s_setprio(0);
      if (t < 14) { WAITV(6); } else { WAITV(0); }
      BAR();
      ushortT* tp;
      tp = Ca; Ca = Na; Na = Za; Za = tp;
      tp = Cb; Cb = Nb; Nb = Zb; Zb = tp;
      tp = Cc; Cc = Nc; Nc = Zc; Zc = tp;
    }
#pragma unroll
    for (int tt = 0; tt < 4; ++tt) {
      const size_t prow = (size_t)(p0 + wA + tt * 16 + lr) * CC;
#pragma unroll
      for (int ss = 0; ss < 4; ++ss) {
        const int co = c0 + wB + ss * 16 + r4;
        float4 b1v = *(const float4*)&bh[co];
        float4 b2v = *(const float4*)&bg[co];
        ushort4 v1, v2;
        v1.x = f2bf(a1[ss][tt][0] + b1v.x);
        v1.y = f2bf(a1[ss][tt][1] + b1v.y);
        v1.z = f2bf(a1[ss][tt][2] + b1v.z);
        v1.w = f2bf(a1[ss][tt][3] + b1v.w);
        v2.x = f2bf(a2[ss][tt][0] + b2v.x);
        v2.y = f2bf(a2[ss][tt][1] + b2v.y);
        v2.z = f2bf(a2[ss][tt][2] + b2v.z);
        v2.w = f2bf(a2[ss][tt][3] + b2v.w);
        *(ushort4*)&o1[prow + co] = v1;
        *(ushort4*)&o2[prow + co] = v2;
      }
    }
  } else if (zq < 4) {             // ---- mask conv: phm [c][s] ----
    const int zb = zq - 2;
    const int s0 = ptile * 128, c0 = ctile * 128;
    const ushortT* Am = maskT + (size_t)zb * PPC + (size_t)s0 * CC;
    const ushortT* Bw = Whbf + (size_t)c0 * CC;
    ushortT* o = phmB + (size_t)zb * PPC;
    f32x4 a[4][4] = {};
    stage(Am, Ca); stage(Bw, Cb);
    stage(Am + 32, Na); stage(Bw + 32, Nb);
    WAITV(4); BAR();
    for (int t = 0; t < 16; ++t) {
      if (t < 14) {
        const int k = (t + 2) * 32;
        stage(Am + k, Za); stage(Bw + k, Zb);
      }
      short8 fs[4], fc[4];
      ldf(Ca, offL, fs);
      ldf(Cb, offR, fc);
      __builtin_amdgcn_s_setprio(1);
#pragma unroll
      for (int ss = 0; ss < 4; ++ss)
#pragma unroll
        for (int tt = 0; tt < 4; ++tt)
          a[ss][tt] = __builtin_amdgcn_mfma_f32_16x16x32_bf16(fs[ss], fc[tt], a[ss][tt], 0, 0, 0);
      __builtin_amdgcn_s_setprio(0);
      if (t < 14) { WAITV(4); } else { WAITV(0); }
      BAR();
      ushortT* tp;
      tp = Ca; Ca = Na; Na = Za; Za = tp;
      tp = Cb; Cb = Nb; Nb = Zb; Zb = tp;
    }
#pragma unroll
    for (int tt = 0; tt < 4; ++tt) {
      const int c = c0 + wB + tt * 16 + lr;
      const float bi = bh[c];
      const size_t crow = (size_t)c * PP;
#pragma unroll
      for (int ss = 0; ss < 4; ++ss) {
        ushort4 v;
        v.x = f2bf(a[ss][tt][0] + bi);
        v.y = f2bf(a[ss][tt][1] + bi);
        v.z = f2bf(a[ss][tt][2] + bi);
        v.w = f2bf(a[ss][tt][3] + bi);
        *(ushort4*)&o[crow + s0 + wA + ss * 16 + r4] = v;
      }
    }
  } else {                         // ---- m,z pair: out [co][p] ----
    const int zb = zq - 4;
    const int p0 = ptile * 128, c0 = ctile * 128;
    const ushortT* Ax = xT + (size_t)zb * PPC + (size_t)p0 * CC;
    const ushortT* Bw1 = Wmbf + (size_t)c0 * CC;
    const ushortT* Bw2 = Wzbf + (size_t)c0 * CC;
    ushortT* o1 = pmB + (size_t)zb * PPC;
    ushortT* o2 = wzb + (size_t)zb * PPC;
    f32x4 a1[4][4] = {}, a2[4][4] = {};
    stage(Ax, Ca); stage(Bw1, Cb); stage(Bw2, Cc);
    stage(Ax + 32, Na); stage(Bw1 + 32, Nb); stage(Bw2 + 32, Nc);
    WAITV(6); BAR();
    for (int t = 0; t < 16; ++t) {
      if (t < 14) {
        const int k = (t + 2) * 32;
        stage(Ax + k, Za); stage(Bw1 + k, Zb); stage(Bw2 + k, Zc);
      }
      short8 fx[4], fw[4];
      ldf(Ca, offL, fx);
      ldf(Cb, offR, fw);
      __builtin_amdgcn_s_setprio(1);
#pragma unroll
      for (int ss = 0; ss < 4; ++ss)
#pragma unroll
        for (int tt = 0; tt < 4; ++tt)
          a1[ss][tt] = __builtin_amdgcn_mfma_f32_16x16x32_bf16(fx[ss], fw[tt], a1[ss][tt], 0, 0, 0);
      __builtin_amdgcn_s_setprio(0);
      ldf(Cc, offR, fw);
      __builtin_amdgcn_s_setprio(1);
#pragma unroll
      for (int ss = 0; ss < 4; ++ss)
#pragma unroll
        for (int tt = 0; tt < 4; ++tt)
          a2[ss][tt] = __builtin_amdgcn_mfma_f32_16x16x32_bf16(fx[ss], fw[tt], a2[ss][tt], 0, 0, 0);
      __builtin_amdgcn_s_setprio(0);
      if (t < 14) { WAITV(6); } else { WAITV(0); }
      BAR();
      ushortT* tp;
      tp = Ca; Ca = Na; Na = Za; Za = tp;
      tp = Cb; Cb = Nb; Nb = Zb; Zb = tp;
      tp = Cc; Cc = Nc; Nc = Zc; Zc = tp;
    }
#pragma unroll
    for (int tt = 0; tt < 4; ++tt) {
      const int c = c0 + wB + tt * 16 + lr;
      const float b1v = bm[c], b2v = bz[c];
      const size_t crow = (size_t)c * PP;
#pragma unroll
      for (int ss = 0; ss < 4; ++ss) {
        const size_t off = crow + p0 + wA + ss * 16 + r4;
        ushort4 v1, v2;
        v1.x = f2bf(a1[ss][tt][0] + b1v);
        v1.y = f2bf(a1[ss][tt][1] + b1v);
        v1.z = f2bf(a1[ss][tt][2] + b1v);
        v1.w = f2bf(a1[ss][tt][3] + b1v);
        v2.x = f2bf(a2[ss][tt][0] + b2v);
        v2.y = f2bf(a2[ss][tt][1] + b2v);
        v2.z = f2bf(a2[ss][tt][2] + b2v);
        v2.w = f2bf(a2[ss][tt][3] + b2v);
        *(ushort4*)&o1[off] = v1;
        *(ushort4*)&o2[off] = v2;
      }
    }
  }
}

// ---------------------------------------------------------------------------
// Combined dispatch A: Energy GEMM (3-deep R7 body, blocks < nE) plus
// grid-stride meadd for the PREVIOUS chunk (256 trailing blocks).
// Dependencies: meadd(chM) reads mePart/rowZ written in the previous
// dispatch; E writes Ech/Estat which prior M/zcomb already consumed.
// ---------------------------------------------------------------------------
template <int KSPT>
__global__ __launch_bounds__(256, 3) void k_eadd(
    const ushortT* __restrict__ phxT, const ushortT* __restrict__ pgT,
    ushortT* __restrict__ Ech, float* __restrict__ Estat,
    int tbaseE, int tilesE, int nE,
    const ushortT* __restrict__ mePart, const float* __restrict__ rowZ,
    ushortT* __restrict__ meb, int tbaseM, int rowsM) {
  __shared__ __align__(16) ushortT smem[24576];   // 6 x 8KB (A,B x 3 bufs)
  __shared__ float Ss[128][2];
  const int tid = threadIdx.x;
  if ((int)blockIdx.x >= nE) {
    // ---- meadd(chM): grid-stride over NN*CC*rowsM/4 quads ----
    const int total4 = NN * CC * rowsM / 4;
    for (int e4 = ((int)blockIdx.x - nE) * 256 + tid; e4 < total4; e4 += 65536) {
      const int idx = e4 * 4;
      const int tl = idx % rowsM;
      const int c = (idx / rowsM) % CC;
      const int z = idx / (rowsM * CC);
      float s0 = 0.f, s1 = 0.f, s2 = 0.f, s3 = 0.f;
#pragma unroll
      for (int ks = 0; ks < KSPT; ++ks) {
        const size_t o = ((size_t)(ks * NN + z) * CC + c) * TCHMAX + tl;
        ushort4 a = *(const ushort4*)&mePart[o];
        s0 += bf2f(a.x); s1 += bf2f(a.y); s2 += bf2f(a.z); s3 += bf2f(a.w);
      }
      const float4 rz = *(const float4*)&rowZ[z * TCHMAX + tl];
      ushort4 v;
      v.x = f2bf(s0 * rz.x); v.y = f2bf(s1 * rz.y);
      v.z = f2bf(s2 * rz.z); v.w = f2bf(s3 * rz.w);
      *(ushort4*)&meb[((size_t)z * CC + c) * PP + tbaseM + tl] = v;
    }
    return;
  }
  // ---- energy body (R7 3-deep, orig = blockIdx.x flattened) ----
  const int l = tid & 63, w = tid >> 6;
  const int orig = blockIdx.x;
  const int wgid = xcd_remap(orig, NJT * tilesE * NN);
  const int it = wgid % tilesE;
  const int jt = (wgid / tilesE) % NJT;
  const int z = wgid / (tilesE * NJT);
  const int j0 = jt * 128;
  const int i0 = it * 128;
  const ushortT* Arow = phxT + (size_t)z * PPC + (size_t)(tbaseE + i0) * CC;
  const ushortT* Brow = pgT + (size_t)z * PPC + (size_t)j0 * CC;
  ushortT* out = Ech + (size_t)z * TCHMAX * PP;
  const int wi = (w & 1) * 64, wj = (w >> 1) * 64;
  const int lr = l & 15, lk = l >> 4;
  const int r4 = (l >> 4) * 4;
  const int srow = l >> 2;
  const int sg8 = ((l & 3) ^ ((l >> 3) & 3)) * 8;
  const int rg16 = (lk ^ ((lr >> 1) & 3)) * 16;

  int offA[4], offB[4];
#pragma unroll
  for (int t = 0; t < 4; ++t) {
    offA[t] = (wi + t * 16 + lr) * 64 + rg16;
    offB[t] = (wj + t * 16 + lr) * 64 + rg16;
  }
  auto stage = [&](const ushortT* src, ushortT* dst) {
#pragma unroll
    for (int i = 0; i < 2; ++i)
      ld_g2l(src + (size_t)(w * 32 + i * 16 + srow) * CC + sg8,
             (char*)dst + (w * 2 + i) * 1024);
  };

  ushortT* Ac = smem;          ushortT* An = smem + 4096;  ushortT* Az = smem + 8192;
  ushortT* Bc = smem + 12288;  ushortT* Bn = smem + 16384; ushortT* Bz = smem + 20480;

  f32x4 acc[4][4] = {};   // [ss][tt]: reg-dim = s, lane-dim = t

  stage(Arow, Ac); stage(Brow, Bc);
  stage(Arow + 32, An); stage(Brow + 32, Bn);
  WAITV(4); BAR();
  for (int t = 0; t < 16; ++t) {
    if (t < 14) {
      const int k = (t + 2) * 32;
      stage(Arow + k, Az); stage(Brow + k, Bz);
    }
    short8 af[4], bfv[4];
#pragma unroll
    for (int tt = 0; tt < 4; ++tt)
      af[tt] = *(const short8*)((const char*)Ac + offA[tt]);
#pragma unroll
    for (int ss = 0; ss < 4; ++ss)
      bfv[ss] = *(const short8*)((const char*)Bc + offB[ss]);
    __builtin_amdgcn_s_setprio(1);
#pragma unroll
    for (int ss = 0; ss < 4; ++ss)
#pragma unroll
      for (int tt = 0; tt < 4; ++tt)
        acc[ss][tt] = __builtin_amdgcn_mfma_f32_16x16x32_bf16(bfv[ss], af[tt], acc[ss][tt], 0, 0, 0);
    __builtin_amdgcn_s_setprio(0);
    if (t < 14) { WAITV(4); } else { WAITV(0); }
    BAR();
    ushortT* tp;
    tp = Ac; Ac = An; An = Az; Az = tp;
    tp = Bc; Bc = Bn; Bn = Bz; Bz = tp;
  }
  // epilogue: exp + direct 8B stores + row-sum (2 shuffles per t-row)
#pragma unroll
  for (int tt = 0; tt < 4; ++tt) {
    const int trow = i0 + wi + tt * 16 + lr;
    ushortT* orow = out + (size_t)trow * PP + j0;
    float sx = 0.f;
#pragma unroll
    for (int ss = 0; ss < 4; ++ss) {
      float u0 = __expf(acc[ss][tt][0] - EM);
      float u1 = __expf(acc[ss][tt][1] - EM);
      float u2 = __expf(acc[ss][tt][2] - EM);
      float u3 = __expf(acc[ss][tt][3] - EM);
      sx += (u0 + u1) + (u2 + u3);
      ushort4 v;
      v.x = f2bf(u0); v.y = f2bf(u1); v.z = f2bf(u2); v.w = f2bf(u3);
      *(ushort4*)&orow[wj + ss * 16 + r4] = v;
    }
    sx += __shfl_xor(sx, 16);
    sx += __shfl_xor(sx, 32);
    if (l < 16) Ss[wi + tt * 16 + l][w >> 1] = sx;
  }
  __syncthreads();
  if (tid < 128) {
    Estat[((size_t)z * TCHMAX + i0 + tid) * NJT + jt] = Ss[tid][0] + Ss[tid][1];
  }
}

// ---------------------------------------------------------------------------
// Combined dispatch B: me partial GEMM (3-deep R7 body, blocks < nM) plus
// zcomb for the SAME chunk (trailing blocks; both depend only on E(ch)).
// ---------------------------------------------------------------------------
template <int KSPT>
__global__ __launch_bounds__(256, 3) void k_mezc(
    const ushortT* __restrict__ phmB, const ushortT* __restrict__ Ech,
    ushortT* __restrict__ mePart, int gxM, int nM,
    const float* __restrict__ Estat, float* __restrict__ rowZ, int rows) {
  __shared__ __align__(16) ushortT smem[18432];   // A 3x8KB + B 3x4KB
  const int tid = threadIdx.x;
  if ((int)blockIdx.x >= nM) {
    // ---- zcomb(ch): 1/Z per row ----
    const int r = ((int)blockIdx.x - nM) * 256 + tid;
    if (r >= NN * rows) return;
    const int z = r / rows, tl = r % rows;
    const float* p = Estat + ((size_t)z * TCHMAX + tl) * NJT;
    float s = 0.f;
#pragma unroll
    for (int j = 0; j < NJT; ++j) s += p[j];
    rowZ[z * TCHMAX + tl] = 1.0f / s;
    return;
  }
  // ---- me body (R7 3-deep, orig = blockIdx.x flattened) ----
  const int l = tid & 63, w = tid >> 6;
  const int orig = blockIdx.x;
  const int nwg = gxM * 4 * (NN * KSPT);
  const int wgid = (orig & 7) * (nwg >> 3) + (orig >> 3);  // nwg % 8 == 0
  const int cb = wgid & 3;
  const int tl = (wgid >> 2) % gxM;
  const int bz = (wgid >> 2) / gxM;
  const int tl0 = tl * 64;
  const int c0 = cb * 128;
  const int z = bz / KSPT, ks = bz % KSPT;
  const ushortT* Arow = phmB + (size_t)z * PPC + (size_t)c0 * PP;
  const ushortT* Brow = Ech + (size_t)z * TCHMAX * PP + (size_t)tl0 * PP;
  const int wc = (w & 1) * 64, wt = (w >> 1) * 32;
  const int lr = l & 15, lk = l >> 4;
  const int r4 = (l >> 4) * 4;
  const int srow = l >> 2;
  const int sg8 = ((l & 3) ^ ((l >> 3) & 3)) * 8;
  const int rg16 = (lk ^ ((lr >> 1) & 3)) * 16;

  int offA[4], offB[2];
#pragma unroll
  for (int t = 0; t < 4; ++t) offA[t] = (wc + t * 16 + lr) * 64 + rg16;
#pragma unroll
  for (int t = 0; t < 2; ++t) offB[t] = (wt + t * 16 + lr) * 64 + rg16;

  auto stA = [&](const ushortT* src, ushortT* dst) {   // 128 rows
#pragma unroll
    for (int i = 0; i < 2; ++i)
      ld_g2l(src + (size_t)(w * 32 + i * 16 + srow) * PP + sg8,
             (char*)dst + (w * 2 + i) * 1024);
  };
  auto stB = [&](const ushortT* src, ushortT* dst) {   // 64 rows
    ld_g2l(src + (size_t)(w * 16 + srow) * PP + sg8, (char*)dst + w * 1024);
  };

  ushortT* Ac = smem;          ushortT* An = smem + 4096;  ushortT* Az = smem + 8192;
  ushortT* Bc = smem + 12288;  ushortT* Bn = smem + 14336; ushortT* Bz = smem + 16384;

  f32x4 acc[2][4] = {};   // [tt][ct]: reg-dim = t, lane-dim = c

  const int sBeg = ((ks * 98) / KSPT) * 64;
  const int sEnd = (((ks + 1) * 98) / KSPT) * 64;
  const int NT = (sEnd - sBeg) >> 5;

  stA(Arow + sBeg, Ac); stB(Brow + sBeg, Bc);
  stA(Arow + sBeg + 32, An); stB(Brow + sBeg + 32, Bn);
  WAITV(3); BAR();
  for (int t = 0; t < NT; ++t) {
    if (t + 2 < NT) {
      const int k = sBeg + (t + 2) * 32;
      stA(Arow + k, Az); stB(Brow + k, Bz);
    }
    short8 af[4], bfv[2];
#pragma unroll
    for (int ct = 0; ct < 4; ++ct)
      af[ct] = *(const short8*)((const char*)Ac + offA[ct]);
#pragma unroll
    for (int tt = 0; tt < 2; ++tt)
      bfv[tt] = *(const short8*)((const char*)Bc + offB[tt]);
    __builtin_amdgcn_s_setprio(1);
#pragma unroll
    for (int tt = 0; tt < 2; ++tt)
#pragma unroll
      for (int ct = 0; ct < 4; ++ct)
        acc[tt][ct] = __builtin_amdgcn_mfma_f32_16x16x32_bf16(bfv[tt], af[ct], acc[tt][ct], 0, 0, 0);
    __builtin_amdgcn_s_setprio(0);
    if (t + 2 < NT) { WAITV(3); } else { WAITV(0); }
    BAR();
    ushortT* tp;
    tp = Ac; Ac = An; An = Az; Az = tp;
    tp = Bc; Bc = Bn; Bn = Bz; Bz = tp;
  }
  ushortT* out = mePart + ((size_t)(ks * NN + z) * CC) * TCHMAX;
#pragma unroll
  for (int ct = 0; ct < 4; ++ct) {
    const size_t crow = (size_t)(c0 + wc + ct * 16 + lr) * TCHMAX + tl0;
#pragma unroll
    for (int tt = 0; tt < 2; ++tt) {
      ushort4 v;
      v.x = f2bf(acc[tt][ct][0]);
      v.y = f2bf(acc[tt][ct][1]);
      v.z = f2bf(acc[tt][ct][2]);
      v.w = f2bf(acc[tt][ct][3]);
      *(ushort4*)&out[crow + wt + tt * 16 + r4] = v;
    }
  }
}

// ---------------------------------------------------------------------------
// standalone meadd (final chunk only)
// ---------------------------------------------------------------------------
template <int KSPT>
__global__ __launch_bounds__(256) void k_meadd(const ushortT* __restrict__ mePart,
                                               const float* __restrict__ rowZ,
                                               ushortT* __restrict__ meb,
                                               int tbase, int rows) {
  const int idx = (blockIdx.x * 256 + threadIdx.x) * 4;   // over NN*CC*rows
  const int tl = idx % rows;
  const int c = (idx / rows) % CC;
  const int z = idx / (rows * CC);
  float s0 = 0.f, s1 = 0.f, s2 = 0.f, s3 = 0.f;
#pragma unroll
  for (int ks = 0; ks < KSPT; ++ks) {
    const size_t o = ((size_t)(ks * NN + z) * CC + c) * TCHMAX + tl;
    ushort4 a = *(const ushort4*)&mePart[o];
    s0 += bf2f(a.x); s1 += bf2f(a.y); s2 += bf2f(a.z); s3 += bf2f(a.w);
  }
  const float4 rz = *(const float4*)&rowZ[z * TCHMAX + tl];
  ushort4 v;
  v.x = f2bf(s0 * rz.x); v.y = f2bf(s1 * rz.y);
  v.z = f2bf(s2 * rz.z); v.w = f2bf(s3 * rz.w);
  *(ushort4*)&meb[((size_t)z * CC + c) * PP + tbase + tl] = v;
}

// ---------------------------------------------------------------------------
// stats: fused me-softmax stats (blocks < NN*CC) + BatchNorm stats (rest)
// ---------------------------------------------------------------------------
__global__ __launch_bounds__(256) void k_stats(const ushortT* __restrict__ me,
                                               const ushortT* __restrict__ wz,
                                               float* __restrict__ m2,
                                               float* __restrict__ Z2,
                                               float* __restrict__ mu,
                                               float* __restrict__ rinv) {
  __shared__ float red[256];
  __shared__ float rq[256];
  const int tid = threadIdx.x;
  const int NCH = PP / 8;
  if ((int)blockIdx.x < NN * CC) {
    const ushortT* row = me + (size_t)blockIdx.x * PP;
    float m = -INFINITY;
    for (int i = tid; i < NCH; i += 256) {
      short8 v = *(const short8*)&row[i * 8];
#pragma unroll
      for (int j = 0; j < 8; ++j) m = fmaxf(m, bf2f((ushortT)v[j]));
    }
    red[tid] = m;
    __syncthreads();
    for (int s = 128; s > 0; s >>= 1) {
      if (tid < s) red[tid] = fmaxf(red[tid], red[tid + s]);
      __syncthreads();
    }
    m = red[0];
    __syncthreads();
    float zz = 0.f;
    for (int i = tid; i < NCH; i += 256) {
      short8 v = *(const short8*)&row[i * 8];
#pragma unroll
      for (int j = 0; j < 8; ++j) zz += __expf(bf2f((ushortT)v[j]) - m);
    }
    red[tid] = zz;
    __syncthreads();
    for (int s = 128; s > 0; s >>= 1) {
      if (tid < s) red[tid] += red[tid + s];
      __syncthreads();
    }
    if (tid == 0) { m2[blockIdx.x] = m; Z2[blockIdx.x] = red[0]; }
  } else {
    const int c = blockIdx.x - NN * CC;
    float s = 0.f, q = 0.f;
    for (int n = 0; n < NN; ++n) {
      const ushortT* rowp = wz + (size_t)n * CC * PP + (size_t)c * PP;
      for (int i = tid; i < NCH; i += 256) {
        short8 v = *(const short8*)&rowp[i * 8];
#pragma unroll
        for (int j = 0; j < 8; ++j) {
          float f = bf2f((ushortT)v[j]);
          s += f;
          q += f * f;
        }
      }
    }
    red[tid] = s; rq[tid] = q;
    __syncthreads();
    for (int st = 128; st > 0; st >>= 1) {
      if (tid < st) { red[tid] += red[tid + st]; rq[tid] += rq[tid + st]; }
      __syncthreads();
    }
    if (tid == 0) {
      const float inv_n = 1.0f / (float)(NN * PP);
      float mean = red[0] * inv_n;
      float var = rq[0] * inv_n - mean * mean;
      mu[c] = mean;
      rinv[c] = rsqrtf(var + 1e-5f);
    }
  }
}

__global__ __launch_bounds__(256) void k_final(const ushortT* __restrict__ pmB,
                                               const ushortT* __restrict__ me,
                                               const ushortT* __restrict__ wz,
                                               const float* __restrict__ m2,
                                               const float* __restrict__ Z2,
                                               const float* __restrict__ mu,
                                               const float* __restrict__ rinv,
                                               const float* __restrict__ bnw,
                                               const float* __restrict__ bnb,
                                               const float* __restrict__ gamma,
                                               float* __restrict__ out) {
  const int e4 = blockIdx.x * 256 + threadIdx.x;
  const size_t e = (size_t)e4 * 4;
  const int nc = (int)(e / PP);
  const int c = nc & (CC - 1);
  const float m = m2[nc];
  const float rz = 1.0f / Z2[nc];
  const float mub = mu[c];
  const float ri = rinv[c] * bnw[c];
  const float bb = bnb[c];
  const float g = gamma[0];
  ushort4 pv = *(const ushort4*)&pmB[e];
  ushort4 mev = *(const ushort4*)&me[e];
  ushort4 wzv = *(const ushort4*)&wz[e];
  float4 o;
  o.x = g * bf2f(pv.x) * (__expf(bf2f(mev.x) - m) * rz) + (bf2f(wzv.x) - mub) * ri + bb;
  o.y = g * bf2f(pv.y) * (__expf(bf2f(mev.y) - m) * rz) + (bf2f(wzv.y) - mub) * ri + bb;
  o.z = g * bf2f(pv.z) * (__expf(bf2f(mev.z) - m) * rz) + (bf2f(wzv.z) - mub) * ri + bb;
  o.w = g * bf2f(pv.w) * (__expf(bf2f(mev.w) - m) * rz) + (bf2f(wzv.w) - mub) * ri + bb;
  *(float4*)&out[e] = o;
}

// ---------------------------------------------------------------------------
extern "C" void kernel_launch(void* const* d_in, const int* in_sizes, int n_in,
                              void* d_out, int out_size, void* d_ws, size_t ws_size,
                              hipStream_t stream) {
  (void)in_sizes; (void)n_in; (void)out_size;
  const float* x    = (const float*)d_in[0];
  const float* mask = (const float*)d_in[1];
  const float* Wh   = (const float*)d_in[2];
  const float* bh   = (const float*)d_in[3];
  const float* Wg   = (const float*)d_in[4];
  const float* bg   = (const float*)d_in[5];
  const float* Wm   = (const float*)d_in[6];
  const float* bm   = (const float*)d_in[7];
  const float* Wz   = (const float*)d_in[8];
  const float* bz   = (const float*)d_in[9];
  const float* bnw  = (const float*)d_in[10];
  const float* bnb  = (const float*)d_in[11];
  const float* gam  = (const float*)d_in[12];

  // ---- workspace layout ----
  ushortT* wzb  = (ushortT*)d_ws;                // bf16 [n][c][p]
  ushortT* meb  = wzb + NCP;                     // bf16 [n][c][p]
  ushortT* pmB  = meb + NCP;                     // bf16 [n][c][p]
  ushortT* phxT = pmB + NCP;                     // bf16 [n][t][c]
  ushortT* pgT  = phxT + NCP;                    // bf16 [n][s][c]
  ushortT* phmB = pgT + NCP;                     // bf16 [n][c][s]
  ushortT* Wbf  = phmB + NCP;                    // 4 x 512x512 bf16
  ushortT* Whbf = Wbf;
  ushortT* Wgbf = Wbf + 1 * CC * CC;
  ushortT* Wmbf = Wbf + 2 * CC * CC;
  ushortT* Wzbf = Wbf + 3 * CC * CC;
  float* m2    = (float*)(Wbf + 4 * CC * CC);
  float* Z2    = m2 + NN * CC;
  float* mu    = Z2 + NN * CC;
  float* rin   = mu + CC;
  float* Estat = rin + CC;                       // NN*TCHMAX*NJT  ~0.65 MB
  float* rowZ  = Estat + (size_t)NN * TCHMAX * NJT;  // NN*TCHMAX (1/Z)
  float* region = rowZ + (size_t)NN * TCHMAX + 16;
  ushortT* xT    = (ushortT*)region;             // overlay (conv phase) 25.7 MB
  ushortT* maskT = xT + NCP;
  ushortT* Ech    = (ushortT*)region;            // bf16 U [n][TCHMAX][PP] 41.7 MB
  ushortT* mePart = Ech + (size_t)NN * TCHMAX * PP; // bf16 [KSPT][n][c][TCHMAX]

  const size_t regionOffB = (size_t)((char*)region - (char*)d_ws);
  const size_t need8 = regionOffB +
      ((size_t)NN * TCHMAX * PP + 8ull * NN * CC * TCHMAX) * 2;
  const bool k8 = ws_size >= need8;

  // ---- prep: weight casts + transpose casts, one dispatch ----
  k_prep<<<1024 + 196 * 16 * 4, 256, 0, stream>>>(x, mask, Wh, Wg, Wm, Wz,
                                                  Wbf, xT, maskT);

  // ---- all five 1x1 convs in one dispatch ----
  k_convs<<<1176, 256, 0, stream>>>(xT, maskT, Whbf, Wgbf, Wmbf, Wzbf,
                                    bh, bg, bm, bz, phxT, pgT, phmB, pmB, wzb);

  // ---- attention, task-overlapped dispatch chain ----
  // D1: E(0) | D2: M(0)||zc(0) | D3: E(1)||meadd(0) | ... | D9: meadd(3)
  static const int chunkTiles[NCHK] = {13, 12, 12, 12};
  int tb[NCHK];
  {
    int acc = 0;
    for (int ch = 0; ch < NCHK; ++ch) { tb[ch] = acc; acc += chunkTiles[ch] * 128; }
  }
  const int KSPv = k8 ? 8 : 4;
  // D1: E(0) alone
  {
    const int nE = NJT * chunkTiles[0] * NN;
    if (k8)
      k_eadd<8><<<nE, 256, 0, stream>>>(phxT, pgT, Ech, Estat, tb[0],
                                        chunkTiles[0], nE, mePart, rowZ, meb, 0, 0);
    else
      k_eadd<4><<<nE, 256, 0, stream>>>(phxT, pgT, Ech, Estat, tb[0],
                                        chunkTiles[0], nE, mePart, rowZ, meb, 0, 0);
  }
  for (int ch = 0; ch < NCHK; ++ch) {
    const int rows = chunkTiles[ch] * 128;
    const int gxM = rows / 64;
    const int nM = gxM * 4 * NN * KSPv;
    const int zcB = (NN * rows + 255) / 256;
    if (k8)
      k_mezc<8><<<nM + zcB, 256, 0, stream>>>(phmB, Ech, mePart, gxM, nM,
                                              Estat, rowZ, rows);
    else
      k_mezc<4><<<nM + zcB, 256, 0, stream>>>(phmB, Ech, mePart, gxM, nM,
                                              Estat, rowZ, rows);
    if (ch < NCHK - 1) {
      const int tilesN = chunkTiles[ch + 1];
      const int nE = NJT * tilesN * NN;
      if (k8)
        k_eadd<8><<<nE + 256, 256, 0, stream>>>(phxT, pgT, Ech, Estat, tb[ch + 1],
                                                tilesN, nE, mePart, rowZ, meb,
                                                tb[ch], rows);
      else
        k_eadd<4><<<nE + 256, 256, 0, stream>>>(phxT, pgT, Ech, Estat, tb[ch + 1],
                                                tilesN, nE, mePart, rowZ, meb,
                                                tb[ch], rows);
    } else {
      if (k8)
        k_meadd<8><<<NN * CC * rows / 1024, 256, 0, stream>>>(mePart, rowZ, meb,
                                                              tb[ch], rows);
      else
        k_meadd<4><<<NN * CC * rows / 1024, 256, 0, stream>>>(mePart, rowZ, meb,
                                                              tb[ch], rows);
    }
  }

  // ---- fused tails ----
  k_stats<<<NN * CC + CC, 256, 0, stream>>>(meb, wzb, m2, Z2, mu, rin);
  const int total4 = (int)(NCP / 4);
  k_final<<<total4 / 256, 256, 0, stream>>>(pmB, meb, wzb, m2, Z2, mu, rin,
                                            bnw, bnb, gam, (float*)d_out);
}

// Round 10
// 484.142 us; speedup vs baseline: 1.1724x; 1.0640x over previous
//
#include <hip/hip_runtime.h>
#include <hip/hip_bf16.h>
#include <math.h>

#define NN 2
#define CC 512
#define PP 6272            // T*H*W
#define TCHMAX 1664        // max chunk rows (13 tiles of 128)
#define NCHK 4             // chunks: 13,12,12,12 tiles
#define NJT 49             // PP/128 j-tiles per energy row
#define EM 64.0f           // fixed softmax shift (softmax is shift-invariant)
static const size_t PPC = (size_t)PP * CC;   // per-n projection elems
static const size_t NCP = (size_t)NN * PPC;  // 6,422,528

typedef unsigned short ushortT;
typedef __attribute__((ext_vector_type(8))) short short8;   // 8 bf16 = 4 VGPR
typedef __attribute__((ext_vector_type(4))) float f32x4;

// counted waitcnt (T4): keep newest stage in flight across the barrier
#define WAITV(N) asm volatile("s_waitcnt vmcnt(" #N ")" ::: "memory")
#define BAR() __builtin_amdgcn_s_barrier()

__device__ __forceinline__ ushortT f2bf(float f) {
  __hip_bfloat16 h = __float2bfloat16(f);
  return *reinterpret_cast<ushortT*>(&h);
}
__device__ __forceinline__ float bf2f(ushortT u) {
  return __uint_as_float(((unsigned)u) << 16);
}

// async global->LDS, 16B/lane. LDS dest = wave-uniform base + lane*16.
__device__ __forceinline__ void ld_g2l(const void* g, void* l) {
  __builtin_amdgcn_global_load_lds(
      (const __attribute__((address_space(1))) void*)g,
      (__attribute__((address_space(3))) void*)l, 16, 0, 0);
}

// bijective XCD-chunked remap (m204)
__device__ __forceinline__ int xcd_remap(int orig, int nwg) {
  const int q = nwg >> 3, r = nwg & 7;
  const int x = orig & 7, lo = orig >> 3;
  return (x < r) ? x * (q + 1) + lo : r * (q + 1) + (x - r) * q + lo;
}

// ---------------------------------------------------------------------------
// BK=32 staging. LDS tile [rows][32k], row stride 64B, XOR swizzle
// g ^= (row>>1)&3; store-side lane const (l>>3)&3, read-side (lr>>1)&3.
// All GEMMs: 3-deep counted pipeline (R5/R7 structure; 4-deep at lower
// occupancy measured WORSE in R8). R10: k_me tile 64t -> 128t (16 MFMA per
// barrier, LDS still 48KB -> 3 blk/CU; pure amortization, no occupancy cost).
// ---------------------------------------------------------------------------

// ---------------------------------------------------------------------------
// prep: fused weight-cast (blocks <1024) + transpose-cast x/mask (rest)
// ---------------------------------------------------------------------------
__global__ __launch_bounds__(256) void k_prep(const float* __restrict__ x,
                                              const float* __restrict__ mask,
                                              const float* __restrict__ W0,
                                              const float* __restrict__ W1,
                                              const float* __restrict__ W2,
                                              const float* __restrict__ W3,
                                              ushortT* __restrict__ Wbf,
                                              ushortT* __restrict__ xT,
                                              ushortT* __restrict__ maskT) {
  __shared__ float T[32][33];
  const int tid = threadIdx.x;
  int b = blockIdx.x;
  if (b < 1024) {
    const int by = b >> 8, bx = b & 255;
    const float* src = (by == 0) ? W0 : (by == 1) ? W1 : (by == 2) ? W2 : W3;
    const int i = (bx * 256 + tid) * 4;
    float4 v = *(const float4*)&src[i];
    ushort4 o;
    o.x = f2bf(v.x); o.y = f2bf(v.y); o.z = f2bf(v.z); o.w = f2bf(v.w);
    *(ushort4*)&Wbf[(size_t)by * CC * CC + i] = o;
    return;
  }
  b -= 1024;
  const int bx = b % 196;
  const int by = (b / 196) & 15;
  const int zz = b / (196 * 16);
  const float* in = (zz < 2) ? x : mask;
  ushortT* out = (zz < 2) ? xT : maskT;
  const int p0 = bx * 32, c0 = by * 32;
  const int tx = tid & 31, ty = tid >> 5;
  const size_t nbi = (size_t)(zz & 1) * PPC;
#pragma unroll
  for (int i = 0; i < 4; ++i)
    T[ty + i * 8][tx] = in[nbi + (size_t)(c0 + ty + i * 8) * PP + p0 + tx];
  __syncthreads();
#pragma unroll
  for (int i = 0; i < 4; ++i) {
    int r = ty + i * 8;
    out[nbi + (size_t)(p0 + r) * CC + c0 + tx] = f2bf(T[tx][r]);
  }
}

// ---------------------------------------------------------------------------
// All five 1x1 convs, one dispatch. 3-deep counted-vmcnt pipeline, BK=32.
// (R5 body verbatim — HW-verified.)
// ---------------------------------------------------------------------------
__global__ __launch_bounds__(256, 2) void k_convs(
    const ushortT* __restrict__ xT, const ushortT* __restrict__ maskT,
    const ushortT* __restrict__ Whbf, const ushortT* __restrict__ Wgbf,
    const ushortT* __restrict__ Wmbf, const ushortT* __restrict__ Wzbf,
    const float* __restrict__ bh, const float* __restrict__ bg,
    const float* __restrict__ bm, const float* __restrict__ bz,
    ushortT* __restrict__ phxT, ushortT* __restrict__ pgT,
    ushortT* __restrict__ phmB, ushortT* __restrict__ pmB,
    ushortT* __restrict__ wzb) {
  __shared__ __align__(16) ushortT smem[36864];   // 9 x 8KB (3 mats x 3 bufs)
  const int tid = threadIdx.x;
  const int l = tid & 63, w = tid >> 6;
  const int orig = blockIdx.x;                    // 1176 = 8*147
  const int wgid = (orig & 7) * 147 + (orig >> 3);
  const int zq = wgid / 196;
  const int within = wgid % 196;
  const int ctile = within & 3;
  const int ptile = within >> 2;
  const int wA = (w & 1) * 64, wB = (w >> 1) * 64;
  const int lr = l & 15, lk = l >> 4;
  const int r4 = (l >> 4) * 4;
  const int srow = l >> 2;
  const int sg8 = ((l & 3) ^ ((l >> 3) & 3)) * 8;
  const int rg16 = (lk ^ ((lr >> 1) & 3)) * 16;

  int offL[4], offR[4];
#pragma unroll
  for (int t = 0; t < 4; ++t) {
    offL[t] = (wA + t * 16 + lr) * 64 + rg16;
    offR[t] = (wB + t * 16 + lr) * 64 + rg16;
  }

  auto stage = [&](const ushortT* src, ushortT* dst) {
#pragma unroll
    for (int i = 0; i < 2; ++i)
      ld_g2l(src + (size_t)(w * 32 + i * 16 + srow) * CC + sg8,
             (char*)dst + (w * 2 + i) * 1024);
  };
  auto ldf = [&](const ushortT* base, const int* off, short8* f) {
#pragma unroll
    for (int t = 0; t < 4; ++t)
      f[t] = *(const short8*)((const char*)base + off[t]);
  };

  ushortT* Ca = smem;          ushortT* Na = smem + 4096;  ushortT* Za = smem + 8192;
  ushortT* Cb = smem + 12288;  ushortT* Nb = smem + 16384; ushortT* Zb = smem + 20480;
  ushortT* Cc = smem + 24576;  ushortT* Nc = smem + 28672; ushortT* Zc = smem + 32768;

  if (zq < 2) {                    // ---- h,g pair: out [p][co] ----
    const int zb = zq;
    const int p0 = ptile * 128, c0 = ctile * 128;
    const ushortT* Ax = xT + (size_t)zb * PPC + (size_t)p0 * CC;
    const ushortT* Bw1 = Whbf + (size_t)c0 * CC;
    const ushortT* Bw2 = Wgbf + (size_t)c0 * CC;
    ushortT* o1 = phxT + (size_t)zb * PPC;
    ushortT* o2 = pgT + (size_t)zb * PPC;
    f32x4 a1[4][4] = {}, a2[4][4] = {};
    stage(Ax, Ca); stage(Bw1, Cb); stage(Bw2, Cc);
    stage(Ax + 32, Na); stage(Bw1 + 32, Nb); stage(Bw2 + 32, Nc);
    WAITV(6); BAR();
    for (int t = 0; t < 16; ++t) {
      if (t < 14) {
        const int k = (t + 2) * 32;
        stage(Ax + k, Za); stage(Bw1 + k, Zb); stage(Bw2 + k, Zc);
      }
      short8 fp[4], fw[4];
      ldf(Ca, offL, fp);
      ldf(Cb, offR, fw);
      __builtin_amdgcn_s_setprio(1);
#pragma unroll
      for (int ss = 0; ss < 4; ++ss)
#pragma unroll
        for (int tt = 0; tt < 4; ++tt)
          a1[ss][tt] = __builtin_amdgcn_mfma_f32_16x16x32_bf16(fw[ss], fp[tt], a1[ss][tt], 0, 0, 0);
      __builtin_amdgcn_s_setprio(0);
      ldf(Cc, offR, fw);
      __builtin_amdgcn_s_setprio(1);
#pragma unroll
      for (int ss = 0; ss < 4; ++ss)
#pragma unroll
        for (int tt = 0; tt < 4; ++tt)
          a2[ss][tt] = __builtin_amdgcn_mfma_f32_16x16x32_bf16(fw[ss], fp[tt], a2[ss][tt], 0, 0, 0);
      __builtin_amdgcn_s_setprio(0);
      if (t < 14) { WAITV(6); } else { WAITV(0); }
      BAR();
      ushortT* tp;
      tp = Ca; Ca = Na; Na = Za; Za = tp;
      tp = Cb; Cb = Nb; Nb = Zb; Zb = tp;
      tp = Cc; Cc = Nc; Nc = Zc; Zc = tp;
    }
#pragma unroll
    for (int tt = 0; tt < 4; ++tt) {
      const size_t prow = (size_t)(p0 + wA + tt * 16 + lr) * CC;
#pragma unroll
      for (int ss = 0; ss < 4; ++ss) {
        const int co = c0 + wB + ss * 16 + r4;
        float4 b1v = *(const float4*)&bh[co];
        float4 b2v = *(const float4*)&bg[co];
        ushort4 v1, v2;
        v1.x = f2bf(a1[ss][tt][0] + b1v.x);
        v1.y = f2bf(a1[ss][tt][1] + b1v.y);
        v1.z = f2bf(a1[ss][tt][2] + b1v.z);
        v1.w = f2bf(a1[ss][tt][3] + b1v.w);
        v2.x = f2bf(a2[ss][tt][0] + b2v.x);
        v2.y = f2bf(a2[ss][tt][1] + b2v.y);
        v2.z = f2bf(a2[ss][tt][2] + b2v.z);
        v2.w = f2bf(a2[ss][tt][3] + b2v.w);
        *(ushort4*)&o1[prow + co] = v1;
        *(ushort4*)&o2[prow + co] = v2;
      }
    }
  } else if (zq < 4) {             // ---- mask conv: phm [c][s] ----
    const int zb = zq - 2;
    const int s0 = ptile * 128, c0 = ctile * 128;
    const ushortT* Am = maskT + (size_t)zb * PPC + (size_t)s0 * CC;
    const ushortT* Bw = Whbf + (size_t)c0 * CC;
    ushortT* o = phmB + (size_t)zb * PPC;
    f32x4 a[4][4] = {};
    stage(Am, Ca); stage(Bw, Cb);
    stage(Am + 32, Na); stage(Bw + 32, Nb);
    WAITV(4); BAR();
    for (int t = 0; t < 16; ++t) {
      if (t < 14) {
        const int k = (t + 2) * 32;
        stage(Am + k, Za); stage(Bw + k, Zb);
      }
      short8 fs[4], fc[4];
      ldf(Ca, offL, fs);
      ldf(Cb, offR, fc);
      __builtin_amdgcn_s_setprio(1);
#pragma unroll
      for (int ss = 0; ss < 4; ++ss)
#pragma unroll
        for (int tt = 0; tt < 4; ++tt)
          a[ss][tt] = __builtin_amdgcn_mfma_f32_16x16x32_bf16(fs[ss], fc[tt], a[ss][tt], 0, 0, 0);
      __builtin_amdgcn_s_setprio(0);
      if (t < 14) { WAITV(4); } else { WAITV(0); }
      BAR();
      ushortT* tp;
      tp = Ca; Ca = Na; Na = Za; Za = tp;
      tp = Cb; Cb = Nb; Nb = Zb; Zb = tp;
    }
#pragma unroll
    for (int tt = 0; tt < 4; ++tt) {
      const int c = c0 + wB + tt * 16 + lr;
      const float bi = bh[c];
      const size_t crow = (size_t)c * PP;
#pragma unroll
      for (int ss = 0; ss < 4; ++ss) {
        ushort4 v;
        v.x = f2bf(a[ss][tt][0] + bi);
        v.y = f2bf(a[ss][tt][1] + bi);
        v.z = f2bf(a[ss][tt][2] + bi);
        v.w = f2bf(a[ss][tt][3] + bi);
        *(ushort4*)&o[crow + s0 + wA + ss * 16 + r4] = v;
      }
    }
  } else {                         // ---- m,z pair: out [co][p] ----
    const int zb = zq - 4;
    const int p0 = ptile * 128, c0 = ctile * 128;
    const ushortT* Ax = xT + (size_t)zb * PPC + (size_t)p0 * CC;
    const ushortT* Bw1 = Wmbf + (size_t)c0 * CC;
    const ushortT* Bw2 = Wzbf + (size_t)c0 * CC;
    ushortT* o1 = pmB + (size_t)zb * PPC;
    ushortT* o2 = wzb + (size_t)zb * PPC;
    f32x4 a1[4][4] = {}, a2[4][4] = {};
    stage(Ax, Ca); stage(Bw1, Cb); stage(Bw2, Cc);
    stage(Ax + 32, Na); stage(Bw1 + 32, Nb); stage(Bw2 + 32, Nc);
    WAITV(6); BAR();
    for (int t = 0; t < 16; ++t) {
      if (t < 14) {
        const int k = (t + 2) * 32;
        stage(Ax + k, Za); stage(Bw1 + k, Zb); stage(Bw2 + k, Zc);
      }
      short8 fx[4], fw[4];
      ldf(Ca, offL, fx);
      ldf(Cb, offR, fw);
      __builtin_amdgcn_s_setprio(1);
#pragma unroll
      for (int ss = 0; ss < 4; ++ss)
#pragma unroll
        for (int tt = 0; tt < 4; ++tt)
          a1[ss][tt] = __builtin_amdgcn_mfma_f32_16x16x32_bf16(fx[ss], fw[tt], a1[ss][tt], 0, 0, 0);
      __builtin_amdgcn_s_setprio(0);
      ldf(Cc, offR, fw);
      __builtin_amdgcn_s_setprio(1);
#pragma unroll
      for (int ss = 0; ss < 4; ++ss)
#pragma unroll
        for (int tt = 0; tt < 4; ++tt)
          a2[ss][tt] = __builtin_amdgcn_mfma_f32_16x16x32_bf16(fx[ss], fw[tt], a2[ss][tt], 0, 0, 0);
      __builtin_amdgcn_s_setprio(0);
      if (t < 14) { WAITV(6); } else { WAITV(0); }
      BAR();
      ushortT* tp;
      tp = Ca; Ca = Na; Na = Za; Za = tp;
      tp = Cb; Cb = Nb; Nb = Zb; Zb = tp;
      tp = Cc; Cc = Nc; Nc = Zc; Zc = tp;
    }
#pragma unroll
    for (int tt = 0; tt < 4; ++tt) {
      const int c = c0 + wB + tt * 16 + lr;
      const float b1v = bm[c], b2v = bz[c];
      const size_t crow = (size_t)c * PP;
#pragma unroll
      for (int ss = 0; ss < 4; ++ss) {
        const size_t off = crow + p0 + wA + ss * 16 + r4;
        ushort4 v1, v2;
        v1.x = f2bf(a1[ss][tt][0] + b1v);
        v1.y = f2bf(a1[ss][tt][1] + b1v);
        v1.z = f2bf(a1[ss][tt][2] + b1v);
        v1.w = f2bf(a1[ss][tt][3] + b1v);
        v2.x = f2bf(a2[ss][tt][0] + b2v);
        v2.y = f2bf(a2[ss][tt][1] + b2v);
        v2.z = f2bf(a2[ss][tt][2] + b2v);
        v2.w = f2bf(a2[ss][tt][3] + b2v);
        *(ushort4*)&o1[off] = v1;
        *(ushort4*)&o2[off] = v2;
      }
    }
  }
}

// ---------------------------------------------------------------------------
// Combined dispatch A: Energy GEMM (3-deep R7 body, blocks < nE) plus
// grid-stride meadd for the PREVIOUS chunk (256 trailing blocks).
// ---------------------------------------------------------------------------
template <int KSPT>
__global__ __launch_bounds__(256, 3) void k_eadd(
    const ushortT* __restrict__ phxT, const ushortT* __restrict__ pgT,
    ushortT* __restrict__ Ech, float* __restrict__ Estat,
    int tbaseE, int tilesE, int nE,
    const ushortT* __restrict__ mePart, const float* __restrict__ rowZ,
    ushortT* __restrict__ meb, int tbaseM, int rowsM) {
  __shared__ __align__(16) ushortT smem[24576];   // 6 x 8KB (A,B x 3 bufs)
  __shared__ float Ss[128][2];
  const int tid = threadIdx.x;
  if ((int)blockIdx.x >= nE) {
    // ---- meadd(chM): grid-stride over NN*CC*rowsM/4 quads ----
    const int total4 = NN * CC * rowsM / 4;
    for (int e4 = ((int)blockIdx.x - nE) * 256 + tid; e4 < total4; e4 += 65536) {
      const int idx = e4 * 4;
      const int tl = idx % rowsM;
      const int c = (idx / rowsM) % CC;
      const int z = idx / (rowsM * CC);
      float s0 = 0.f, s1 = 0.f, s2 = 0.f, s3 = 0.f;
#pragma unroll
      for (int ks = 0; ks < KSPT; ++ks) {
        const size_t o = ((size_t)(ks * NN + z) * CC + c) * TCHMAX + tl;
        ushort4 a = *(const ushort4*)&mePart[o];
        s0 += bf2f(a.x); s1 += bf2f(a.y); s2 += bf2f(a.z); s3 += bf2f(a.w);
      }
      const float4 rz = *(const float4*)&rowZ[z * TCHMAX + tl];
      ushort4 v;
      v.x = f2bf(s0 * rz.x); v.y = f2bf(s1 * rz.y);
      v.z = f2bf(s2 * rz.z); v.w = f2bf(s3 * rz.w);
      *(ushort4*)&meb[((size_t)z * CC + c) * PP + tbaseM + tl] = v;
    }
    return;
  }
  // ---- energy body (R7 3-deep) ----
  const int l = tid & 63, w = tid >> 6;
  const int orig = blockIdx.x;
  const int wgid = xcd_remap(orig, NJT * tilesE * NN);
  const int it = wgid % tilesE;
  const int jt = (wgid / tilesE) % NJT;
  const int z = wgid / (tilesE * NJT);
  const int j0 = jt * 128;
  const int i0 = it * 128;
  const ushortT* Arow = phxT + (size_t)z * PPC + (size_t)(tbaseE + i0) * CC;
  const ushortT* Brow = pgT + (size_t)z * PPC + (size_t)j0 * CC;
  ushortT* out = Ech + (size_t)z * TCHMAX * PP;
  const int wi = (w & 1) * 64, wj = (w >> 1) * 64;
  const int lr = l & 15, lk = l >> 4;
  const int r4 = (l >> 4) * 4;
  const int srow = l >> 2;
  const int sg8 = ((l & 3) ^ ((l >> 3) & 3)) * 8;
  const int rg16 = (lk ^ ((lr >> 1) & 3)) * 16;

  int offA[4], offB[4];
#pragma unroll
  for (int t = 0; t < 4; ++t) {
    offA[t] = (wi + t * 16 + lr) * 64 + rg16;
    offB[t] = (wj + t * 16 + lr) * 64 + rg16;
  }
  auto stage = [&](const ushortT* src, ushortT* dst) {
#pragma unroll
    for (int i = 0; i < 2; ++i)
      ld_g2l(src + (size_t)(w * 32 + i * 16 + srow) * CC + sg8,
             (char*)dst + (w * 2 + i) * 1024);
  };

  ushortT* Ac = smem;          ushortT* An = smem + 4096;  ushortT* Az = smem + 8192;
  ushortT* Bc = smem + 12288;  ushortT* Bn = smem + 16384; ushortT* Bz = smem + 20480;

  f32x4 acc[4][4] = {};   // [ss][tt]: reg-dim = s, lane-dim = t

  stage(Arow, Ac); stage(Brow, Bc);
  stage(Arow + 32, An); stage(Brow + 32, Bn);
  WAITV(4); BAR();
  for (int t = 0; t < 16; ++t) {
    if (t < 14) {
      const int k = (t + 2) * 32;
      stage(Arow + k, Az); stage(Brow + k, Bz);
    }
    short8 af[4], bfv[4];
#pragma unroll
    for (int tt = 0; tt < 4; ++tt)
      af[tt] = *(const short8*)((const char*)Ac + offA[tt]);
#pragma unroll
    for (int ss = 0; ss < 4; ++ss)
      bfv[ss] = *(const short8*)((const char*)Bc + offB[ss]);
    __builtin_amdgcn_s_setprio(1);
#pragma unroll
    for (int ss = 0; ss < 4; ++ss)
#pragma unroll
      for (int tt = 0; tt < 4; ++tt)
        acc[ss][tt] = __builtin_amdgcn_mfma_f32_16x16x32_bf16(bfv[ss], af[tt], acc[ss][tt], 0, 0, 0);
    __builtin_amdgcn_s_setprio(0);
    if (t < 14) { WAITV(4); } else { WAITV(0); }
    BAR();
    ushortT* tp;
    tp = Ac; Ac = An; An = Az; Az = tp;
    tp = Bc; Bc = Bn; Bn = Bz; Bz = tp;
  }
  // epilogue: exp + direct 8B stores + row-sum (2 shuffles per t-row)
#pragma unroll
  for (int tt = 0; tt < 4; ++tt) {
    const int trow = i0 + wi + tt * 16 + lr;
    ushortT* orow = out + (size_t)trow * PP + j0;
    float sx = 0.f;
#pragma unroll
    for (int ss = 0; ss < 4; ++ss) {
      float u0 = __expf(acc[ss][tt][0] - EM);
      float u1 = __expf(acc[ss][tt][1] - EM);
      float u2 = __expf(acc[ss][tt][2] - EM);
      float u3 = __expf(acc[ss][tt][3] - EM);
      sx += (u0 + u1) + (u2 + u3);
      ushort4 v;
      v.x = f2bf(u0); v.y = f2bf(u1); v.z = f2bf(u2); v.w = f2bf(u3);
      *(ushort4*)&orow[wj + ss * 16 + r4] = v;
    }
    sx += __shfl_xor(sx, 16);
    sx += __shfl_xor(sx, 32);
    if (l < 16) Ss[wi + tt * 16 + l][w >> 1] = sx;
  }
  __syncthreads();
  if (tid < 128) {
    Estat[((size_t)z * TCHMAX + i0 + tid) * NJT + jt] = Ss[tid][0] + Ss[tid][1];
  }
}

// ---------------------------------------------------------------------------
// Combined dispatch B: me partial GEMM (128c x 128t tile, 3-deep, 16 MFMA
// per barrier — R10 change) plus zcomb for the SAME chunk (trailing blocks).
// Ledger (4 loads/iter): prologue tiles 0,1 (8 loads), WAITV(4) -> tile0
// done. Iter: stage t+2 (4 loads), compute, WAITV(4); tail WAITV(0).
// grid (rows/128 x 4 x NN*KSPT) + zcomb blocks. LDS 48KB -> 3 blk/CU.
// ---------------------------------------------------------------------------
template <int KSPT>
__global__ __launch_bounds__(256, 3) void k_mezc(
    const ushortT* __restrict__ phmB, const ushortT* __restrict__ Ech,
    ushortT* __restrict__ mePart, int gxM, int nM,
    const float* __restrict__ Estat, float* __restrict__ rowZ, int rows) {
  __shared__ __align__(16) ushortT smem[24576];   // A 3x8KB + B 3x8KB
  const int tid = threadIdx.x;
  if ((int)blockIdx.x >= nM) {
    // ---- zcomb(ch): 1/Z per row ----
    const int r = ((int)blockIdx.x - nM) * 256 + tid;
    if (r >= NN * rows) return;
    const int z = r / rows, tl = r % rows;
    const float* p = Estat + ((size_t)z * TCHMAX + tl) * NJT;
    float s = 0.f;
#pragma unroll
    for (int j = 0; j < NJT; ++j) s += p[j];
    rowZ[z * TCHMAX + tl] = 1.0f / s;
    return;
  }
  // ---- me body: 128c x 128t tile ----
  const int l = tid & 63, w = tid >> 6;
  const int orig = blockIdx.x;
  const int nwg = gxM * 4 * (NN * KSPT);
  const int wgid = (orig & 7) * (nwg >> 3) + (orig >> 3);  // nwg % 8 == 0
  const int cb = wgid & 3;
  const int tl = (wgid >> 2) % gxM;
  const int bz = (wgid >> 2) / gxM;
  const int tl0 = tl * 128;
  const int c0 = cb * 128;
  const int z = bz / KSPT, ks = bz % KSPT;
  const ushortT* Arow = phmB + (size_t)z * PPC + (size_t)c0 * PP;
  const ushortT* Brow = Ech + (size_t)z * TCHMAX * PP + (size_t)tl0 * PP;
  const int wc = (w & 1) * 64, wt = (w >> 1) * 64;
  const int lr = l & 15, lk = l >> 4;
  const int r4 = (l >> 4) * 4;
  const int srow = l >> 2;
  const int sg8 = ((l & 3) ^ ((l >> 3) & 3)) * 8;
  const int rg16 = (lk ^ ((lr >> 1) & 3)) * 16;

  int offA[4], offB[4];
#pragma unroll
  for (int t = 0; t < 4; ++t) {
    offA[t] = (wc + t * 16 + lr) * 64 + rg16;
    offB[t] = (wt + t * 16 + lr) * 64 + rg16;
  }

  // both operands: 128 rows x 32k, stride PP
  auto st128 = [&](const ushortT* src, ushortT* dst) {
#pragma unroll
    for (int i = 0; i < 2; ++i)
      ld_g2l(src + (size_t)(w * 32 + i * 16 + srow) * PP + sg8,
             (char*)dst + (w * 2 + i) * 1024);
  };

  ushortT* Ac = smem;          ushortT* An = smem + 4096;  ushortT* Az = smem + 8192;
  ushortT* Bc = smem + 12288;  ushortT* Bn = smem + 16384; ushortT* Bz = smem + 20480;

  f32x4 acc[4][4] = {};   // [tt][ct]: reg-dim = t, lane-dim = c

  const int sBeg = ((ks * 98) / KSPT) * 64;
  const int sEnd = (((ks + 1) * 98) / KSPT) * 64;
  const int NT = (sEnd - sBeg) >> 5;

  st128(Arow + sBeg, Ac); st128(Brow + sBeg, Bc);
  st128(Arow + sBeg + 32, An); st128(Brow + sBeg + 32, Bn);
  WAITV(4); BAR();
  for (int t = 0; t < NT; ++t) {
    if (t + 2 < NT) {
      const int k = sBeg + (t + 2) * 32;
      st128(Arow + k, Az); st128(Brow + k, Bz);
    }
    short8 af[4], bfv[4];
#pragma unroll
    for (int ct = 0; ct < 4; ++ct)
      af[ct] = *(const short8*)((const char*)Ac + offA[ct]);
#pragma unroll
    for (int tt = 0; tt < 4; ++tt)
      bfv[tt] = *(const short8*)((const char*)Bc + offB[tt]);
    __builtin_amdgcn_s_setprio(1);
#pragma unroll
    for (int tt = 0; tt < 4; ++tt)
#pragma unroll
      for (int ct = 0; ct < 4; ++ct)
        acc[tt][ct] = __builtin_amdgcn_mfma_f32_16x16x32_bf16(bfv[tt], af[ct], acc[tt][ct], 0, 0, 0);
    __builtin_amdgcn_s_setprio(0);
    if (t + 2 < NT) { WAITV(4); } else { WAITV(0); }
    BAR();
    ushortT* tp;
    tp = Ac; Ac = An; An = Az; Az = tp;
    tp = Bc; Bc = Bn; Bn = Bz; Bz = tp;
  }
  ushortT* out = mePart + ((size_t)(ks * NN + z) * CC) * TCHMAX;
#pragma unroll
  for (int ct = 0; ct < 4; ++ct) {
    const size_t crow = (size_t)(c0 + wc + ct * 16 + lr) * TCHMAX + tl0;
#pragma unroll
    for (int tt = 0; tt < 4; ++tt) {
      ushort4 v;
      v.x = f2bf(acc[tt][ct][0]);
      v.y = f2bf(acc[tt][ct][1]);
      v.z = f2bf(acc[tt][ct][2]);
      v.w = f2bf(acc[tt][ct][3]);
      *(ushort4*)&out[crow + wt + tt * 16 + r4] = v;
    }
  }
}

// ---------------------------------------------------------------------------
// standalone meadd (final chunk only)
// ---------------------------------------------------------------------------
template <int KSPT>
__global__ __launch_bounds__(256) void k_meadd(const ushortT* __restrict__ mePart,
                                               const float* __restrict__ rowZ,
                                               ushortT* __restrict__ meb,
                                               int tbase, int rows) {
  const int idx = (blockIdx.x * 256 + threadIdx.x) * 4;   // over NN*CC*rows
  const int tl = idx % rows;
  const int c = (idx / rows) % CC;
  const int z = idx / (rows * CC);
  float s0 = 0.f, s1 = 0.f, s2 = 0.f, s3 = 0.f;
#pragma unroll
  for (int ks = 0; ks < KSPT; ++ks) {
    const size_t o = ((size_t)(ks * NN + z) * CC + c) * TCHMAX + tl;
    ushort4 a = *(const ushort4*)&mePart[o];
    s0 += bf2f(a.x); s1 += bf2f(a.y); s2 += bf2f(a.z); s3 += bf2f(a.w);
  }
  const float4 rz = *(const float4*)&rowZ[z * TCHMAX + tl];
  ushort4 v;
  v.x = f2bf(s0 * rz.x); v.y = f2bf(s1 * rz.y);
  v.z = f2bf(s2 * rz.z); v.w = f2bf(s3 * rz.w);
  *(ushort4*)&meb[((size_t)z * CC + c) * PP + tbase + tl] = v;
}

// ---------------------------------------------------------------------------
// stats: fused me-softmax stats (blocks < NN*CC) + BatchNorm stats (rest)
// ---------------------------------------------------------------------------
__global__ __launch_bounds__(256) void k_stats(const ushortT* __restrict__ me,
                                               const ushortT* __restrict__ wz,
                                               float* __restrict__ m2,
                                               float* __restrict__ Z2,
                                               float* __restrict__ mu,
                                               float* __restrict__ rinv) {
  __shared__ float red[256];
  __shared__ float rq[256];
  const int tid = threadIdx.x;
  const int NCH = PP / 8;
  if ((int)blockIdx.x < NN * CC) {
    const ushortT* row = me + (size_t)blockIdx.x * PP;
    float m = -INFINITY;
    for (int i = tid; i < NCH; i += 256) {
      short8 v = *(const short8*)&row[i * 8];
#pragma unroll
      for (int j = 0; j < 8; ++j) m = fmaxf(m, bf2f((ushortT)v[j]));
    }
    red[tid] = m;
    __syncthreads();
    for (int s = 128; s > 0; s >>= 1) {
      if (tid < s) red[tid] = fmaxf(red[tid], red[tid + s]);
      __syncthreads();
    }
    m = red[0];
    __syncthreads();
    float zz = 0.f;
    for (int i = tid; i < NCH; i += 256) {
      short8 v = *(const short8*)&row[i * 8];
#pragma unroll
      for (int j = 0; j < 8; ++j) zz += __expf(bf2f((ushortT)v[j]) - m);
    }
    red[tid] = zz;
    __syncthreads();
    for (int s = 128; s > 0; s >>= 1) {
      if (tid < s) red[tid] += red[tid + s];
      __syncthreads();
    }
    if (tid == 0) { m2[blockIdx.x] = m; Z2[blockIdx.x] = red[0]; }
  } else {
    const int c = blockIdx.x - NN * CC;
    float s = 0.f, q = 0.f;
    for (int n = 0; n < NN; ++n) {
      const ushortT* rowp = wz + (size_t)n * CC * PP + (size_t)c * PP;
      for (int i = tid; i < NCH; i += 256) {
        short8 v = *(const short8*)&rowp[i * 8];
#pragma unroll
        for (int j = 0; j < 8; ++j) {
          float f = bf2f((ushortT)v[j]);
          s += f;
          q += f * f;
        }
      }
    }
    red[tid] = s; rq[tid] = q;
    __syncthreads();
    for (int st = 128; st > 0; st >>= 1) {
      if (tid < st) { red[tid] += red[tid + st]; rq[tid] += rq[tid + st]; }
      __syncthreads();
    }
    if (tid == 0) {
      const float inv_n = 1.0f / (float)(NN * PP);
      float mean = red[0] * inv_n;
      float var = rq[0] * inv_n - mean * mean;
      mu[c] = mean;
      rinv[c] = rsqrtf(var + 1e-5f);
    }
  }
}

__global__ __launch_bounds__(256) void k_final(const ushortT* __restrict__ pmB,
                                               const ushortT* __restrict__ me,
                                               const ushortT* __restrict__ wz,
                                               const float* __restrict__ m2,
                                               const float* __restrict__ Z2,
                                               const float* __restrict__ mu,
                                               const float* __restrict__ rinv,
                                               const float* __restrict__ bnw,
                                               const float* __restrict__ bnb,
                                               const float* __restrict__ gamma,
                                               float* __restrict__ out) {
  const int e4 = blockIdx.x * 256 + threadIdx.x;
  const size_t e = (size_t)e4 * 4;
  const int nc = (int)(e / PP);
  const int c = nc & (CC - 1);
  const float m = m2[nc];
  const float rz = 1.0f / Z2[nc];
  const float mub = mu[c];
  const float ri = rinv[c] * bnw[c];
  const float bb = bnb[c];
  const float g = gamma[0];
  ushort4 pv = *(const ushort4*)&pmB[e];
  ushort4 mev = *(const ushort4*)&me[e];
  ushort4 wzv = *(const ushort4*)&wz[e];
  float4 o;
  o.x = g * bf2f(pv.x) * (__expf(bf2f(mev.x) - m) * rz) + (bf2f(wzv.x) - mub) * ri + bb;
  o.y = g * bf2f(pv.y) * (__expf(bf2f(mev.y) - m) * rz) + (bf2f(wzv.y) - mub) * ri + bb;
  o.z = g * bf2f(pv.z) * (__expf(bf2f(mev.z) - m) * rz) + (bf2f(wzv.z) - mub) * ri + bb;
  o.w = g * bf2f(pv.w) * (__expf(bf2f(mev.w) - m) * rz) + (bf2f(wzv.w) - mub) * ri + bb;
  *(float4*)&out[e] = o;
}

// ---------------------------------------------------------------------------
extern "C" void kernel_launch(void* const* d_in, const int* in_sizes, int n_in,
                              void* d_out, int out_size, void* d_ws, size_t ws_size,
                              hipStream_t stream) {
  (void)in_sizes; (void)n_in; (void)out_size;
  const float* x    = (const float*)d_in[0];
  const float* mask = (const float*)d_in[1];
  const float* Wh   = (const float*)d_in[2];
  const float* bh   = (const float*)d_in[3];
  const float* Wg   = (const float*)d_in[4];
  const float* bg   = (const float*)d_in[5];
  const float* Wm   = (const float*)d_in[6];
  const float* bm   = (const float*)d_in[7];
  const float* Wz   = (const float*)d_in[8];
  const float* bz   = (const float*)d_in[9];
  const float* bnw  = (const float*)d_in[10];
  const float* bnb  = (const float*)d_in[11];
  const float* gam  = (const float*)d_in[12];

  // ---- workspace layout ----
  ushortT* wzb  = (ushortT*)d_ws;                // bf16 [n][c][p]
  ushortT* meb  = wzb + NCP;                     // bf16 [n][c][p]
  ushortT* pmB  = meb + NCP;                     // bf16 [n][c][p]
  ushortT* phxT = pmB + NCP;                     // bf16 [n][t][c]
  ushortT* pgT  = phxT + NCP;                    // bf16 [n][s][c]
  ushortT* phmB = pgT + NCP;                     // bf16 [n][c][s]
  ushortT* Wbf  = phmB + NCP;                    // 4 x 512x512 bf16
  ushortT* Whbf = Wbf;
  ushortT* Wgbf = Wbf + 1 * CC * CC;
  ushortT* Wmbf = Wbf + 2 * CC * CC;
  ushortT* Wzbf = Wbf + 3 * CC * CC;
  float* m2    = (float*)(Wbf + 4 * CC * CC);
  float* Z2    = m2 + NN * CC;
  float* mu    = Z2 + NN * CC;
  float* rin   = mu + CC;
  float* Estat = rin + CC;                       // NN*TCHMAX*NJT  ~0.65 MB
  float* rowZ  = Estat + (size_t)NN * TCHMAX * NJT;  // NN*TCHMAX (1/Z)
  float* region = rowZ + (size_t)NN * TCHMAX + 16;
  ushortT* xT    = (ushortT*)region;             // overlay (conv phase) 25.7 MB
  ushortT* maskT = xT + NCP;
  ushortT* Ech    = (ushortT*)region;            // bf16 U [n][TCHMAX][PP] 41.7 MB
  ushortT* mePart = Ech + (size_t)NN * TCHMAX * PP; // bf16 [KSPT][n][c][TCHMAX]

  const size_t regionOffB = (size_t)((char*)region - (char*)d_ws);
  const size_t need8 = regionOffB +
      ((size_t)NN * TCHMAX * PP + 8ull * NN * CC * TCHMAX) * 2;
  const bool k8 = ws_size >= need8;

  // ---- prep: weight casts + transpose casts, one dispatch ----
  k_prep<<<1024 + 196 * 16 * 4, 256, 0, stream>>>(x, mask, Wh, Wg, Wm, Wz,
                                                  Wbf, xT, maskT);

  // ---- all five 1x1 convs in one dispatch ----
  k_convs<<<1176, 256, 0, stream>>>(xT, maskT, Whbf, Wgbf, Wmbf, Wzbf,
                                    bh, bg, bm, bz, phxT, pgT, phmB, pmB, wzb);

  // ---- attention, task-overlapped dispatch chain ----
  // D1: E(0) | D2: M(0)||zc(0) | D3: E(1)||meadd(0) | ... | D9: meadd(3)
  static const int chunkTiles[NCHK] = {13, 12, 12, 12};
  int tb[NCHK];
  {
    int acc = 0;
    for (int ch = 0; ch < NCHK; ++ch) { tb[ch] = acc; acc += chunkTiles[ch] * 128; }
  }
  const int KSPv = k8 ? 8 : 4;
  // D1: E(0) alone
  {
    const int nE = NJT * chunkTiles[0] * NN;
    if (k8)
      k_eadd<8><<<nE, 256, 0, stream>>>(phxT, pgT, Ech, Estat, tb[0],
                                        chunkTiles[0], nE, mePart, rowZ, meb, 0, 0);
    else
      k_eadd<4><<<nE, 256, 0, stream>>>(phxT, pgT, Ech, Estat, tb[0],
                                        chunkTiles[0], nE, mePart, rowZ, meb, 0, 0);
  }
  for (int ch = 0; ch < NCHK; ++ch) {
    const int rows = chunkTiles[ch] * 128;
    const int gxM = rows / 128;                  // 128-row t-tiles
    const int nM = gxM * 4 * NN * KSPv;
    const int zcB = (NN * rows + 255) / 256;
    if (k8)
      k_mezc<8><<<nM + zcB, 256, 0, stream>>>(phmB, Ech, mePart, gxM, nM,
                                              Estat, rowZ, rows);
    else
      k_mezc<4><<<nM + zcB, 256, 0, stream>>>(phmB, Ech, mePart, gxM, nM,
                                              Estat, rowZ, rows);
    if (ch < NCHK - 1) {
      const int tilesN = chunkTiles[ch + 1];
      const int nE = NJT * tilesN * NN;
      if (k8)
        k_eadd<8><<<nE + 256, 256, 0, stream>>>(phxT, pgT, Ech, Estat, tb[ch + 1],
                                                tilesN, nE, mePart, rowZ, meb,
                                                tb[ch], rows);
      else
        k_eadd<4><<<nE + 256, 256, 0, stream>>>(phxT, pgT, Ech, Estat, tb[ch + 1],
                                                tilesN, nE, mePart, rowZ, meb,
                                                tb[ch], rows);
    } else {
      if (k8)
        k_meadd<8><<<NN * CC * rows / 1024, 256, 0, stream>>>(mePart, rowZ, meb,
                                                              tb[ch], rows);
      else
        k_meadd<4><<<NN * CC * rows / 1024, 256, 0, stream>>>(mePart, rowZ, meb,
                                                              tb[ch], rows);
    }
  }

  // ---- fused tails ----
  k_stats<<<NN * CC + CC, 256, 0, stream>>>(meb, wzb, m2, Z2, mu, rin);
  const int total4 = (int)(NCP / 4);
  k_final<<<total4 / 256, 256, 0, stream>>>(pmB, meb, wzb, m2, Z2, mu, rin,
                                            bnw, bnb, gam, (float*)d_out);
}